// Round 1
// baseline (3767.978 us; speedup 1.0000x reference)
//
#include <hip/hip_runtime.h>
#include <stdint.h>

// ============================================================================
// SynthID watermark processor: replicate JAX threefry2x32 RNG exactly, apply
// 16 watermark depth updates to softmax probs, top-p(0.9) sample via
// gumbel-argmax over sorted order, emit 1e-5 / 1e5 scores.
//
// RNG MODE BET (round 1): jax_threefry_partitionable = True (modern JAX
// default): random_bits(i) = y0^y1 of TF(key, (0,i)); split is fold-like.
// If absmax ~1e5, flip PARTITIONABLE to 0 next round (classic halves scheme).
// ============================================================================

#define PARTITIONABLE 1

#define NB 32
#define NV 128000
#define NHALF 64000
#define NDEPTH 16
#define NBKT 65536
#define NCHUNK 125   // NV / 1024

__device__ __forceinline__ uint32_t rotl32(uint32_t v, int r) {
  return (v << r) | (v >> (32 - r));
}

// Threefry-2x32, 20 rounds (JAX/Random123 constants).
__device__ __forceinline__ void tf2x32(uint32_t k0, uint32_t k1,
                                       uint32_t x0, uint32_t x1,
                                       uint32_t &o0, uint32_t &o1) {
  uint32_t ks2 = k0 ^ k1 ^ 0x1BD11BDAu;
  x0 += k0; x1 += k1;
  x0 += x1; x1 = rotl32(x1, 13); x1 ^= x0;
  x0 += x1; x1 = rotl32(x1, 15); x1 ^= x0;
  x0 += x1; x1 = rotl32(x1, 26); x1 ^= x0;
  x0 += x1; x1 = rotl32(x1,  6); x1 ^= x0;
  x0 += k1; x1 += ks2 + 1u;
  x0 += x1; x1 = rotl32(x1, 17); x1 ^= x0;
  x0 += x1; x1 = rotl32(x1, 29); x1 ^= x0;
  x0 += x1; x1 = rotl32(x1, 16); x1 ^= x0;
  x0 += x1; x1 = rotl32(x1, 24); x1 ^= x0;
  x0 += ks2; x1 += k0 + 2u;
  x0 += x1; x1 = rotl32(x1, 13); x1 ^= x0;
  x0 += x1; x1 = rotl32(x1, 15); x1 ^= x0;
  x0 += x1; x1 = rotl32(x1, 26); x1 ^= x0;
  x0 += x1; x1 = rotl32(x1,  6); x1 ^= x0;
  x0 += k0; x1 += k1 + 3u;
  x0 += x1; x1 = rotl32(x1, 17); x1 ^= x0;
  x0 += x1; x1 = rotl32(x1, 29); x1 ^= x0;
  x0 += x1; x1 = rotl32(x1, 16); x1 ^= x0;
  x0 += x1; x1 = rotl32(x1, 24); x1 ^= x0;
  x0 += k1; x1 += ks2 + 4u;
  x0 += x1; x1 = rotl32(x1, 13); x1 ^= x0;
  x0 += x1; x1 = rotl32(x1, 15); x1 ^= x0;
  x0 += x1; x1 = rotl32(x1, 26); x1 ^= x0;
  x0 += x1; x1 = rotl32(x1,  6); x1 ^= x0;
  x0 += ks2; x1 += k0 + 5u;
  o0 = x0; o1 = x1;
}

// jax random_bits(key, 32, (NV,)) element i.
__device__ __forceinline__ uint32_t random_bits32(uint32_t k0, uint32_t k1, uint32_t i) {
#if PARTITIONABLE
  uint32_t y0, y1;
  tf2x32(k0, k1, 0u, i, y0, y1);
  return y0 ^ y1;
#else
  uint32_t y0, y1;
  if (i < NHALF) { tf2x32(k0, k1, i, i + NHALF, y0, y1); return y0; }
  tf2x32(k0, k1, i - NHALF, i, y0, y1);
  return y1;
#endif
}

// ---------------------------------------------------------------------------
// K0: zero the histogram region
__global__ void zero_k(uint32_t* __restrict__ p, size_t n) {
  size_t i = (size_t)blockIdx.x * 256 + threadIdx.x;
  if (i < n) p[i] = 0u;
}

// K1: per-batch key chains: k_b = fold_in(key(0), prior); k_bd = fold_in(k_b, d);
//     sample keys = split(key(1), 32)[b]. Also zero `best`.
__global__ void keys_k(const int* __restrict__ ids, int T,
                       uint32_t* __restrict__ kd, uint32_t* __restrict__ sk,
                       unsigned long long* __restrict__ best) {
  int t = threadIdx.x;
  if (t >= NB) return;
  uint32_t prior = 0;
  for (int q = 0; q < 4; ++q) prior += (uint32_t)ids[(size_t)t * T + (T - 4) + q];
  uint32_t b0, b1;
  tf2x32(0u, 0u, 0u, prior, b0, b1);            // fold_in(key(0), prior)
  for (int d = 0; d < NDEPTH; ++d) {
    uint32_t y0, y1;
    tf2x32(b0, b1, 0u, (uint32_t)d, y0, y1);    // fold_in(k_b, d)
    kd[(t * NDEPTH + d) * 2 + 0] = y0;
    kd[(t * NDEPTH + d) * 2 + 1] = y1;
  }
#if PARTITIONABLE
  uint32_t s0, s1;
  tf2x32(0u, 1u, 0u, (uint32_t)t, s0, s1);      // fold-like split of key(1)
  sk[2 * t + 0] = s0;
  sk[2 * t + 1] = s1;
#else
  {
    uint32_t c0 = 2u * (uint32_t)t, c1 = 2u * (uint32_t)t + 1u;
    uint32_t s0, s1, z;
    if (c0 < 32u) tf2x32(0u, 1u, c0, c0 + 32u, s0, z);
    else          tf2x32(0u, 1u, c0 - 32u, c0, z, s0);
    if (c1 < 32u) tf2x32(0u, 1u, c1, c1 + 32u, s1, z);
    else          tf2x32(0u, 1u, c1 - 32u, c1, z, s1);
    sk[2 * t + 0] = s0;
    sk[2 * t + 1] = s1;
  }
#endif
  best[t] = 0ull;
}

// K2: softmax per batch (one block per batch)
__global__ void softmax_k(const float* __restrict__ logits, float* __restrict__ probs) {
  int b = blockIdx.x, t = threadIdx.x;
  const float* x = logits + (size_t)b * NV;
  float* p = probs + (size_t)b * NV;
  __shared__ float red[1024];
  float m = -3.4e38f;
  for (int v = t; v < NV; v += 1024) m = fmaxf(m, x[v]);
  red[t] = m; __syncthreads();
  for (int s = 512; s > 0; s >>= 1) { if (t < s) red[t] = fmaxf(red[t], red[t + s]); __syncthreads(); }
  m = red[0];
  __syncthreads();
  float sum = 0.f;
  for (int v = t; v < NV; v += 1024) sum += expf(x[v] - m);
  red[t] = sum; __syncthreads();
  for (int s = 512; s > 0; s >>= 1) { if (t < s) red[t] += red[t + s]; __syncthreads(); }
  float Z = red[0];
  for (int v = t; v < NV; v += 1024) p[v] = expf(x[v] - m) / Z;
}

// K3: g bitmask per (batch, vocab): bit d = bernoulli(0.5) draw at depth d.
//     bernoulli(0.5) true <=> top bit of 32-bit draw == 0.
__global__ void gmask_k(const uint32_t* __restrict__ kd, uint16_t* __restrict__ mask) {
  int blk = blockIdx.x;
  int b = blk / (NV / 256);
  int v = (blk % (NV / 256)) * 256 + threadIdx.x;
  __shared__ uint32_t lk[NDEPTH * 2];
  if (threadIdx.x < NDEPTH * 2) lk[threadIdx.x] = kd[b * NDEPTH * 2 + threadIdx.x];
  __syncthreads();
  uint32_t m = 0;
  for (int d = 0; d < NDEPTH; ++d) {
    uint32_t bits = random_bits32(lk[2 * d], lk[2 * d + 1], (uint32_t)v);
    m |= (((bits >> 31) == 0u) ? 1u : 0u) << d;
  }
  mask[(size_t)b * NV + v] = (uint16_t)m;
}

// K4: 16 sequential depth updates: gm = sum(g*p); p *= (1 + g - gm)
__global__ void depth_k(float* __restrict__ probs, const uint16_t* __restrict__ mask) {
  int b = blockIdx.x, t = threadIdx.x;
  float* p = probs + (size_t)b * NV;
  const uint16_t* mk = mask + (size_t)b * NV;
  __shared__ float red[1024];
  for (int d = 0; d < NDEPTH; ++d) {
    float local = 0.f;
    for (int v = t; v < NV; v += 1024)
      local += ((mk[v] >> d) & 1) ? p[v] : 0.f;
    red[t] = local; __syncthreads();
    for (int s = 512; s > 0; s >>= 1) { if (t < s) red[t] += red[t + s]; __syncthreads(); }
    float gm = red[0];
    __syncthreads();
    // thread t only ever touches v === t (mod 1024): no cross-thread dep on p
    for (int v = t; v < NV; v += 1024) {
      float g = (float)((mk[v] >> d) & 1);
      p[v] = p[v] * (1.0f + g - gm);
    }
    __syncthreads();
  }
}

// K5: bucket histogram over top 16 bits of float pattern (p >= 0 -> monotone)
__global__ void hist_k(const float* __restrict__ probs, uint32_t* __restrict__ hist) {
  size_t i = (size_t)blockIdx.x * 256 + threadIdx.x;
  int b = (int)(i / NV);
  uint32_t bits = __float_as_uint(probs[i]);
  atomicAdd(&hist[(size_t)b * NBKT + (bits >> 16)], 1u);
}

// K6: per-batch DESCENDING exclusive scan of 65536 buckets, in place.
//     hist[bkt] becomes "# tokens in strictly-higher buckets" (= segment start);
//     cursor gets a copy (advanced by K7's scatter to become segment end).
__global__ void scan_k(uint32_t* __restrict__ hist, uint32_t* __restrict__ cursor) {
  int b = blockIdx.x, t = threadIdx.x;
  uint32_t* h = hist + (size_t)b * NBKT;
  uint32_t* c = cursor + (size_t)b * NBKT;
  int hi = NBKT - t * 64;
  int lo = hi - 64;
  uint32_t s = 0;
  for (int k = lo; k < hi; ++k) s += h[k];
  __shared__ uint32_t sc[1024];
  sc[t] = s;
  __syncthreads();
  for (int off = 1; off < 1024; off <<= 1) {
    uint32_t v = (t >= off) ? sc[t - off] : 0u;
    __syncthreads();
    sc[t] += v;
    __syncthreads();
  }
  uint32_t run = sc[t] - s;   // exclusive: sum over higher-bucket threads
  for (int k = hi - 1; k >= lo; --k) {
    uint32_t cnt = h[k];
    h[k] = run;
    c[k] = run;
    run += cnt;
  }
}

// K7: scatter token ids into bucket member lists (order within bucket arbitrary)
__global__ void scatter_k(const float* __restrict__ probs, uint32_t* __restrict__ cursor,
                          uint32_t* __restrict__ blist) {
  size_t i = (size_t)blockIdx.x * 256 + threadIdx.x;
  int b = (int)(i / NV);
  int v = (int)(i % NV);
  uint32_t bits = __float_as_uint(probs[i]);
  uint32_t pos = atomicAdd(&cursor[(size_t)b * NBKT + (bits >> 16)], 1u);
  blist[(size_t)b * NV + pos] = (uint32_t)v;
}

// K8: exact rank via intra-bucket comparison ((bits desc, index asc) total order)
//     and scatter into sorted arrays. sortp lives in d_out (overwritten later).
__global__ void rank_k(const float* __restrict__ probs, const uint32_t* __restrict__ prefix,
                       const uint32_t* __restrict__ endc, const uint32_t* __restrict__ blist,
                       float* __restrict__ sortp, uint32_t* __restrict__ sidx) {
  size_t i = (size_t)blockIdx.x * 256 + threadIdx.x;
  int b = (int)(i / NV);
  int v = (int)(i % NV);
  const float* p = probs + (size_t)b * NV;
  float pe = p[v];
  uint32_t Ke = __float_as_uint(pe);
  uint32_t bkt = Ke >> 16;
  uint32_t start = prefix[(size_t)b * NBKT + bkt];
  uint32_t end   = endc[(size_t)b * NBKT + bkt];
  const uint32_t* bl = blist + (size_t)b * NV;
  uint32_t less = 0;
  for (uint32_t pos = start; pos < end; ++pos) {
    uint32_t f = bl[pos];
    uint32_t Kf = __float_as_uint(p[f]);
    less += (Kf > Ke || (Kf == Ke && f < (uint32_t)v)) ? 1u : 0u;
  }
  uint32_t r = start + less;
  sortp[(size_t)b * NV + r] = pe;
  sidx[(size_t)b * NV + r] = (uint32_t)v;
}

// K9: per-1024 chunk sums of sorted probs (f64)
__global__ void chunks_k(const float* __restrict__ sp, double* __restrict__ cs) {
  int blk = blockIdx.x;
  int b = blk / NCHUNK, c = blk % NCHUNK;
  const float* p = sp + (size_t)b * NV + (size_t)c * 1024;
  double s = 0.0;
  for (int k = threadIdx.x; k < 1024; k += 256) s += (double)p[k];
  __shared__ double red[256];
  red[threadIdx.x] = s; __syncthreads();
  for (int st = 128; st > 0; st >>= 1) {
    if (threadIdx.x < st) red[threadIdx.x] += red[threadIdx.x + st];
    __syncthreads();
  }
  if (threadIdx.x == 0) cs[b * NCHUNK + c] = red[0];
}

// K10: cutoff = searchsorted(cumsum(sorted_p), 0.9f, 'left') per batch
__global__ void cutoff_k(const float* __restrict__ sp, const double* __restrict__ cs,
                         uint32_t* __restrict__ cut) {
  int b = threadIdx.x;
  if (b >= NB) return;
  const double TOPP = (double)0.9f;   // match f32(0.9) threshold
  double run = 0.0;
  uint32_t c = NV - 1;
  bool found = false;
  for (int ch = 0; ch < NCHUNK && !found; ++ch) {
    double s = cs[b * NCHUNK + ch];
    if (run + s < TOPP - 1e-6) { run += s; continue; }
    const float* p = sp + (size_t)b * NV + (size_t)ch * 1024;
    for (int k = 0; k < 1024; ++k) {
      run += (double)p[k];
      if (run >= TOPP) { c = (uint32_t)(ch * 1024 + k); found = true; break; }
    }
  }
  cut[b] = c;
}

// K11: gumbel-argmax over kept sorted positions j <= cutoff.
//      score = log(sorted_p[j]) + gumbel_j  (top-p renorm is a uniform shift).
__global__ void argmax_k(const float* __restrict__ sortp, const uint32_t* __restrict__ cut,
                         const uint32_t* __restrict__ sk,
                         unsigned long long* __restrict__ best) {
  const int SUB = 16;
  int b = blockIdx.x / SUB;
  int s = blockIdx.x % SUB;
  uint32_t c = cut[b];
  uint32_t k0 = sk[2 * b], k1 = sk[2 * b + 1];
  unsigned long long loc = 0ull;
  for (uint32_t j = (uint32_t)(s * 256 + threadIdx.x); j <= c; j += SUB * 256) {
    uint32_t bits = random_bits32(k0, k1, j);
    uint32_t m = bits >> 9;
    // jax uniform(minval=tiny, maxval=1): u = m*2^-23, or tiny when m == 0
    float u = (m == 0u) ? 1.17549435e-38f : (float)m * 1.1920928955078125e-7f;
    float gum = -logf(-logf(u));
    float scv = logf(sortp[(size_t)b * NV + j]) + gum;
    uint32_t su = __float_as_uint(scv);
    uint32_t ord = (su & 0x80000000u) ? ~su : (su | 0x80000000u);
    // tie -> smaller j wins (jnp.argmax first-max semantics)
    unsigned long long pk = ((unsigned long long)ord << 32) |
                            (unsigned long long)(0xFFFFFFFFu - j);
    loc = (pk > loc) ? pk : loc;
  }
  __shared__ unsigned long long red[256];
  red[threadIdx.x] = loc;
  __syncthreads();
  for (int st = 128; st > 0; st >>= 1) {
    if (threadIdx.x < st) {
      unsigned long long o = red[threadIdx.x + st];
      if (o > red[threadIdx.x]) red[threadIdx.x] = o;
    }
    __syncthreads();
  }
  if (threadIdx.x == 0) atomicMax(best + b, red[0]);
}

// K12: fill output with 1e-5 (after argmax has consumed sorted_p from d_out)
__global__ void fill_k(float* __restrict__ out) {
  size_t i = (size_t)blockIdx.x * 256 + threadIdx.x;
  out[i] = 1e-5f;
}

// K13: write the winner
__global__ void win_k(const unsigned long long* __restrict__ best,
                      const uint32_t* __restrict__ sidx, float* __restrict__ out) {
  int b = threadIdx.x;
  if (b >= NB) return;
  unsigned long long pk = best[b];
  uint32_t j = 0xFFFFFFFFu - (uint32_t)(pk & 0xFFFFFFFFull);
  uint32_t tok = sidx[(size_t)b * NV + j];
  out[(size_t)b * NV + tok] = 100000.0f;
}

// ---------------------------------------------------------------------------

extern "C" void kernel_launch(void* const* d_in, const int* in_sizes, int n_in,
                              void* d_out, int out_size, void* d_ws, size_t ws_size,
                              hipStream_t stream) {
  const int* ids = (const int*)d_in[0];
  const float* logits = (const float*)d_in[1];
  float* out = (float*)d_out;
  int T = in_sizes[0] / NB;   // 2048

  char* w = (char*)d_ws;
  float*    probs  = (float*)(w + 0);                      // 16,384,000 B
  uint16_t* mask   = (uint16_t*)(w + 16384000);            //  8,192,000 B
  uint32_t* hist   = (uint32_t*)(w + 24576000);            //  8,388,608 B
  uint32_t* cursor = (uint32_t*)(w + 32964608);            //  8,388,608 B
  uint32_t* blist  = (uint32_t*)(w + 41353216);            // 16,384,000 B
  uint32_t* sidx   = (uint32_t*)(w + 57737216);            // 16,384,000 B
  double*   csum   = (double*)(w + 74121216);              //     32,000 B
  uint32_t* cut    = (uint32_t*)(w + 74153216);            //        128 B
  unsigned long long* best = (unsigned long long*)(w + 74153344); // 256 B
  uint32_t* kd     = (uint32_t*)(w + 74153600);            //      4,096 B
  uint32_t* sk     = (uint32_t*)(w + 74157696);            //        256 B

  float* sortp = out;   // reuse d_out for sorted probs until final fill

  const size_t BV = (size_t)NB * NV;          // 4,096,000
  const int BVBLK = (int)(BV / 256);          // 16,000

  zero_k<<<(NB * NBKT + 255) / 256, 256, 0, stream>>>(hist, (size_t)NB * NBKT);
  keys_k<<<1, 64, 0, stream>>>(ids, T, kd, sk, best);
  softmax_k<<<NB, 1024, 0, stream>>>(logits, probs);
  gmask_k<<<NB * (NV / 256), 256, 0, stream>>>(kd, mask);
  depth_k<<<NB, 1024, 0, stream>>>(probs, mask);
  hist_k<<<BVBLK, 256, 0, stream>>>(probs, hist);
  scan_k<<<NB, 1024, 0, stream>>>(hist, cursor);
  scatter_k<<<BVBLK, 256, 0, stream>>>(probs, cursor, blist);
  rank_k<<<BVBLK, 256, 0, stream>>>(probs, hist, cursor, blist, sortp, sidx);
  chunks_k<<<NB * NCHUNK, 256, 0, stream>>>(sortp, csum);
  cutoff_k<<<1, 32, 0, stream>>>(sortp, csum, cut);
  argmax_k<<<NB * 16, 256, 0, stream>>>(sortp, cut, sk, best);
  fill_k<<<BVBLK, 256, 0, stream>>>(out);
  win_k<<<1, 32, 0, stream>>>(best, sidx, out);
}

// Round 2
// 996.505 us; speedup vs baseline: 3.7812x; 3.7812x over previous
//
#include <hip/hip_runtime.h>
#include <stdint.h>

// ============================================================================
// SynthID watermark processor — round 2 (performance rewrite).
// RNG: jax_threefry_partitionable=True scheme (validated round 1).
// Pipeline:
//   keys -> gmask(16-bit g per token) -> max -> exp-accumulate into 65536
//   mask-group bins (fixed-point u64, deterministic) -> 16-step group
//   recurrence for gm[16] -> final_k (exact per-token chain, emit radix pairs)
//   -> 4-pass LSD radix sort (stable, descending p, idx tiebreak)
//   -> chunk sums -> top-p cutoff -> gumbel argmax -> scores.
// ============================================================================

#define NB 32
#define NV 128000
#define NDEPTH 16
#define NBLK 125       // radix/max blocks per batch (1024 elems each)
#define NCHUNK 125     // 1024-elem chunks per batch
#define FPSCALE 17592186044416.0   // 2^44

typedef unsigned long long u64;

__device__ __forceinline__ uint32_t rotl32(uint32_t v, int r) {
  return (v << r) | (v >> (32 - r));
}

// Threefry-2x32, 20 rounds.
__device__ __forceinline__ void tf2x32(uint32_t k0, uint32_t k1,
                                       uint32_t x0, uint32_t x1,
                                       uint32_t &o0, uint32_t &o1) {
  uint32_t ks2 = k0 ^ k1 ^ 0x1BD11BDAu;
  x0 += k0; x1 += k1;
  x0 += x1; x1 = rotl32(x1, 13); x1 ^= x0;
  x0 += x1; x1 = rotl32(x1, 15); x1 ^= x0;
  x0 += x1; x1 = rotl32(x1, 26); x1 ^= x0;
  x0 += x1; x1 = rotl32(x1,  6); x1 ^= x0;
  x0 += k1; x1 += ks2 + 1u;
  x0 += x1; x1 = rotl32(x1, 17); x1 ^= x0;
  x0 += x1; x1 = rotl32(x1, 29); x1 ^= x0;
  x0 += x1; x1 = rotl32(x1, 16); x1 ^= x0;
  x0 += x1; x1 = rotl32(x1, 24); x1 ^= x0;
  x0 += ks2; x1 += k0 + 2u;
  x0 += x1; x1 = rotl32(x1, 13); x1 ^= x0;
  x0 += x1; x1 = rotl32(x1, 15); x1 ^= x0;
  x0 += x1; x1 = rotl32(x1, 26); x1 ^= x0;
  x0 += x1; x1 = rotl32(x1,  6); x1 ^= x0;
  x0 += k0; x1 += k1 + 3u;
  x0 += x1; x1 = rotl32(x1, 17); x1 ^= x0;
  x0 += x1; x1 = rotl32(x1, 29); x1 ^= x0;
  x0 += x1; x1 = rotl32(x1, 16); x1 ^= x0;
  x0 += x1; x1 = rotl32(x1, 24); x1 ^= x0;
  x0 += k1; x1 += ks2 + 4u;
  x0 += x1; x1 = rotl32(x1, 13); x1 ^= x0;
  x0 += x1; x1 = rotl32(x1, 15); x1 ^= x0;
  x0 += x1; x1 = rotl32(x1, 26); x1 ^= x0;
  x0 += x1; x1 = rotl32(x1,  6); x1 ^= x0;
  x0 += ks2; x1 += k0 + 5u;
  o0 = x0; o1 = x1;
}

// jax random_bits(key, 32, (n,)) element i — partitionable mode.
__device__ __forceinline__ uint32_t random_bits32(uint32_t k0, uint32_t k1, uint32_t i) {
  uint32_t y0, y1;
  tf2x32(k0, k1, 0u, i, y0, y1);
  return y0 ^ y1;
}

// ---------------------------------------------------------------------------
// K1: per-batch key chains (validated round 1). Also zeroes `best`.
__global__ void keys_k(const int* __restrict__ ids, int T,
                       uint32_t* __restrict__ kd, uint32_t* __restrict__ sk,
                       u64* __restrict__ best) {
  int t = threadIdx.x;
  if (t >= NB) return;
  uint32_t prior = 0;
  for (int q = 0; q < 4; ++q) prior += (uint32_t)ids[(size_t)t * T + (T - 4) + q];
  uint32_t b0, b1;
  tf2x32(0u, 0u, 0u, prior, b0, b1);            // fold_in(key(0), prior)
  for (int d = 0; d < NDEPTH; ++d) {
    uint32_t y0, y1;
    tf2x32(b0, b1, 0u, (uint32_t)d, y0, y1);    // fold_in(k_b, d)
    kd[(t * NDEPTH + d) * 2 + 0] = y0;
    kd[(t * NDEPTH + d) * 2 + 1] = y1;
  }
  uint32_t s0, s1;
  tf2x32(0u, 1u, 0u, (uint32_t)t, s0, s1);      // split(key(1))[t]
  sk[2 * t + 0] = s0;
  sk[2 * t + 1] = s1;
  best[t] = 0ull;
}

// K2: 16-bit bernoulli mask per (batch, token)
__global__ void gmask_k(const uint32_t* __restrict__ kd, uint16_t* __restrict__ mask) {
  int blk = blockIdx.x;
  int b = blk / (NV / 256);
  int v = (blk % (NV / 256)) * 256 + threadIdx.x;
  __shared__ uint32_t lk[NDEPTH * 2];
  if (threadIdx.x < NDEPTH * 2) lk[threadIdx.x] = kd[b * NDEPTH * 2 + threadIdx.x];
  __syncthreads();
  uint32_t m = 0;
  for (int d = 0; d < NDEPTH; ++d) {
    uint32_t bits = random_bits32(lk[2 * d], lk[2 * d + 1], (uint32_t)v);
    m |= (((bits >> 31) == 0u) ? 1u : 0u) << d;
  }
  mask[(size_t)b * NV + v] = (uint16_t)m;
}

// K3a: per-block partial max of logits
__global__ void maxr1_k(const float* __restrict__ logits, float* __restrict__ pmax) {
  int blk = blockIdx.x, b = blk / NBLK, c = blk % NBLK;
  const float* x = logits + (size_t)b * NV + (size_t)c * 1024;
  int t = threadIdx.x;
  float m = fmaxf(fmaxf(x[t], x[t + 256]), fmaxf(x[t + 512], x[t + 768]));
  __shared__ float red[256];
  red[t] = m; __syncthreads();
  for (int s = 128; s > 0; s >>= 1) { if (t < s) red[t] = fmaxf(red[t], red[t + s]); __syncthreads(); }
  if (t == 0) pmax[b * NBLK + c] = red[0];
}

// K3b: finish max (32 lanes per batch)
__global__ void maxr2_k(const float* __restrict__ pmax, float* __restrict__ mx) {
  int t = threadIdx.x;          // 1024 threads: 32 batches x 32 lanes
  int b = t >> 5, k = t & 31;
  float m = -3.4e38f;
  for (int i = k; i < NBLK; i += 32) m = fmaxf(m, pmax[b * NBLK + i]);
  for (int o = 16; o > 0; o >>= 1) m = fmaxf(m, __shfl_xor(m, o, 32));
  if (k == 0) mx[b] = m;
}

// K4: accumulate exp(x - mx) into 65536 mask-group bins, fixed-point u64.
//     Integer atomics => deterministic. ~2 tokens/bin => no contention.
__global__ void expacc_k(const float* __restrict__ logits, const uint16_t* __restrict__ mask,
                         const float* __restrict__ mx, u64* __restrict__ bins) {
  size_t i = (size_t)blockIdx.x * 256 + threadIdx.x;
  int b = blockIdx.x / (NV / 256);
  float e = expf(logits[i] - mx[b]);
  u64 q = (u64)((double)e * FPSCALE);
  atomicAdd(&bins[((size_t)b << 16) | mask[i]], q);
}

// K5: per-batch group recurrence -> gm[16] and f32 partition sum zf.
//     64 groups/thread in registers; 3 barriers per depth.
__launch_bounds__(1024)
__global__ void fac_k(const u64* __restrict__ bins, float* __restrict__ zf,
                      float* __restrict__ gm) {
  int b = blockIdx.x, t = threadIdx.x;
  int w = t >> 6, lane = t & 63;
  const u64* bb = bins + ((size_t)b << 16);

  // exact integer Z
  u64 zp = 0;
  #pragma unroll
  for (int j = 0; j < 64; ++j) zp += bb[t * 64 + j];
  for (int o = 32; o > 0; o >>= 1) zp += __shfl_xor(zp, o);
  __shared__ u64 zw[16];
  if (lane == 0) zw[w] = zp;
  __syncthreads();
  __shared__ double Zsh;
  if (t == 0) {
    u64 zi = 0;
    for (int k = 0; k < 16; ++k) zi += zw[k];
    Zsh = (double)zi * (1.0 / FPSCALE);
  }
  __syncthreads();
  double Zd = Zsh;
  if (t == 0) zf[b] = (float)Zd;

  float cur[64];
  #pragma unroll
  for (int j = 0; j < 64; ++j)
    cur[j] = (float)((double)bb[t * 64 + j] * (1.0 / FPSCALE) / Zd);

  __shared__ double gw[16];
  __shared__ double gsh;
  for (int d = 0; d < NDEPTH; ++d) {
    double part = 0.0;
    #pragma unroll
    for (int j = 0; j < 64; ++j) {
      int m = (t << 6) | j;
      if ((m >> d) & 1) part += (double)cur[j];
    }
    for (int o = 32; o > 0; o >>= 1) part += __shfl_xor(part, o);
    if (lane == 0) gw[w] = part;
    __syncthreads();
    if (t == 0) {
      double s = 0.0;
      for (int k = 0; k < 16; ++k) s += gw[k];
      gsh = s;
    }
    __syncthreads();
    float g = (float)gsh;
    if (t == 0) gm[b * NDEPTH + d] = g;
    #pragma unroll
    for (int j = 0; j < 64; ++j) {
      int m = (t << 6) | j;
      float f = (1.0f + (float)((m >> d) & 1)) - g;
      cur[j] *= f;
    }
    __syncthreads();
  }
}

// K6: exact per-token chain (matches reference association) -> radix pairs.
//     key = ~bits(p): ascending stable sort == descending p, idx-asc ties.
__global__ void final_k(const float* __restrict__ logits, const uint16_t* __restrict__ mask,
                        const float* __restrict__ mx, const float* __restrict__ zf,
                        const float* __restrict__ gm, uint2* __restrict__ pairs) {
  int b = blockIdx.x / (NV / 256);
  __shared__ float gsh[NDEPTH];
  __shared__ float msh, zsh;
  if (threadIdx.x < NDEPTH) gsh[threadIdx.x] = gm[b * NDEPTH + threadIdx.x];
  if (threadIdx.x == 16) msh = mx[b];
  if (threadIdx.x == 17) zsh = zf[b];
  __syncthreads();
  size_t i = (size_t)blockIdx.x * 256 + threadIdx.x;
  int v = (int)(i % NV);
  float p = expf(logits[i] - msh) / zsh;
  uint16_t mk = mask[i];
  #pragma unroll
  for (int d = 0; d < NDEPTH; ++d) {
    float g = (float)((mk >> d) & 1);
    p = p * ((1.0f + g) - gsh[d]);
  }
  uint32_t key = ~__float_as_uint(p);
  pairs[i] = make_uint2(key, (uint32_t)v);
}

// ---------------- LSD radix sort: 4 passes x 8 bits ------------------------

// R1: per-block digit histogram. cnt[(b*256+digit)*125 + blk]
__global__ void rhist_k(const uint2* __restrict__ src, uint32_t* __restrict__ cnt, int shift) {
  int blk = blockIdx.x, b = blk / NBLK, c = blk % NBLK;
  const uint2* s = src + (size_t)b * NV + (size_t)c * 1024;
  int t = threadIdx.x;
  __shared__ uint32_t lh[256];
  lh[t] = 0;
  __syncthreads();
  #pragma unroll
  for (int e = 0; e < 4; ++e) {
    uint32_t k = s[t + 256 * e].x;
    atomicAdd(&lh[(k >> shift) & 255u], 1u);
  }
  __syncthreads();
  cnt[((size_t)b * 256 + t) * NBLK + c] = lh[t];
}

// R2: per-batch exclusive scan over 32000 counts (digit-major, block-minor).
__launch_bounds__(1024)
__global__ void rscan_k(uint32_t* __restrict__ cnt) {
  int b = blockIdx.x, t = threadIdx.x;
  uint32_t* cc = cnt + (size_t)b * 256 * NBLK;   // 32000 entries
  uint32_t loc[32];
  uint32_t s = 0;
  int base = t * 32;
  bool act = base < 256 * NBLK;
  if (act) {
    #pragma unroll
    for (int j = 0; j < 32; ++j) { loc[j] = cc[base + j]; s += loc[j]; }
  }
  __shared__ uint32_t sc[1024];
  sc[t] = s;
  __syncthreads();
  for (int off = 1; off < 1024; off <<= 1) {
    uint32_t v = (t >= off) ? sc[t - off] : 0u;
    __syncthreads();
    sc[t] += v;
    __syncthreads();
  }
  uint32_t run = sc[t] - s;   // exclusive prefix
  if (act) {
    #pragma unroll
    for (int j = 0; j < 32; ++j) { uint32_t o = loc[j]; cc[base + j] = run; run += o; }
  }
}

// R3: stable scatter. Element order (round e, wave w, lane) == memory order.
__launch_bounds__(256)
__global__ void rscatter_k(const uint2* __restrict__ src, uint2* __restrict__ dst,
                           const uint32_t* __restrict__ cnt, int shift) {
  int blk = blockIdx.x, b = blk / NBLK, c = blk % NBLK;
  const uint2* s = src + (size_t)b * NV + (size_t)c * 1024;
  uint2* d = dst + (size_t)b * NV;
  int t = threadIdx.x, w = t >> 6, lane = t & 63;
  __shared__ uint32_t runb[256];
  __shared__ uint32_t wvc[4][256];
  runb[t] = cnt[((size_t)b * 256 + t) * NBLK + c];
  uint2 el[4];
  #pragma unroll
  for (int e = 0; e < 4; ++e) el[e] = s[t + 256 * e];
  u64 lowmask = (1ull << lane) - 1ull;
  #pragma unroll
  for (int e = 0; e < 4; ++e) {
    uint32_t* wf = &wvc[0][0];
    wf[t] = 0; wf[t + 256] = 0; wf[t + 512] = 0; wf[t + 768] = 0;
    __syncthreads();
    uint32_t dig = (el[e].x >> shift) & 255u;
    u64 m = ~0ull;
    #pragma unroll
    for (int bit = 0; bit < 8; ++bit) {
      u64 bb = __ballot((dig >> bit) & 1u);
      m &= ((dig >> bit) & 1u) ? bb : ~bb;
    }
    uint32_t rank = (uint32_t)__popcll(m & lowmask);
    if (rank == 0) wvc[w][dig] = (uint32_t)__popcll(m);
    __syncthreads();
    uint32_t off = runb[dig] + rank;
    for (int w2 = 0; w2 < w; ++w2) off += wvc[w2][dig];
    d[off] = el[e];
    __syncthreads();
    runb[t] += wvc[0][t] + wvc[1][t] + wvc[2][t] + wvc[3][t];
    __syncthreads();
  }
}

// ---------------------------------------------------------------------------
// K7: per-1024-chunk f64 sums of sorted probs
__global__ void chunks_k(const uint2* __restrict__ sp, double* __restrict__ cs) {
  int blk = blockIdx.x;
  int b = blk / NCHUNK, c = blk % NCHUNK;
  const uint2* p = sp + (size_t)b * NV + (size_t)c * 1024;
  double s = 0.0;
  for (int k = threadIdx.x; k < 1024; k += 256)
    s += (double)__uint_as_float(~p[k].x);
  __shared__ double red[256];
  red[threadIdx.x] = s; __syncthreads();
  for (int st = 128; st > 0; st >>= 1) {
    if (threadIdx.x < st) red[threadIdx.x] += red[threadIdx.x + st];
    __syncthreads();
  }
  if (threadIdx.x == 0) cs[b * NCHUNK + c] = red[0];
}

// K8: cutoff = searchsorted(cumsum(sorted_p), 0.9f, 'left')
__global__ void cutoff_k(const uint2* __restrict__ sp, const double* __restrict__ cs,
                         uint32_t* __restrict__ cut) {
  int b = threadIdx.x;
  if (b >= NB) return;
  const double TOPP = (double)0.9f;
  double run = 0.0;
  uint32_t c = NV - 1;
  bool found = false;
  for (int ch = 0; ch < NCHUNK && !found; ++ch) {
    double s = cs[b * NCHUNK + ch];
    if (run + s < TOPP - 1e-6) { run += s; continue; }
    const uint2* p = sp + (size_t)b * NV + (size_t)ch * 1024;
    for (int k = 0; k < 1024; ++k) {
      run += (double)__uint_as_float(~p[k].x);
      if (run >= TOPP) { c = (uint32_t)(ch * 1024 + k); found = true; break; }
    }
  }
  cut[b] = c;
}

// K9: gumbel-argmax over kept sorted positions (top-p renorm is argmax-invariant)
__global__ void argmax_k(const uint2* __restrict__ sp, const uint32_t* __restrict__ cut,
                         const uint32_t* __restrict__ sk, u64* __restrict__ best) {
  const int SUB = 16;
  int b = blockIdx.x / SUB;
  int s = blockIdx.x % SUB;
  uint32_t c = cut[b];
  uint32_t k0 = sk[2 * b], k1 = sk[2 * b + 1];
  u64 loc = 0ull;
  for (uint32_t j = (uint32_t)(s * 256 + threadIdx.x); j <= c; j += SUB * 256) {
    uint32_t bits = random_bits32(k0, k1, j);
    uint32_t m = bits >> 9;
    float u = (m == 0u) ? 1.17549435e-38f : (float)m * 1.1920928955078125e-7f;
    float gum = -logf(-logf(u));
    float scv = logf(__uint_as_float(~sp[(size_t)b * NV + j].x)) + gum;
    uint32_t su = __float_as_uint(scv);
    uint32_t ord = (su & 0x80000000u) ? ~su : (su | 0x80000000u);
    u64 pk = ((u64)ord << 32) | (u64)(0xFFFFFFFFu - j);
    loc = (pk > loc) ? pk : loc;
  }
  __shared__ u64 red[256];
  red[threadIdx.x] = loc;
  __syncthreads();
  for (int st = 128; st > 0; st >>= 1) {
    if (threadIdx.x < st) {
      u64 o = red[threadIdx.x + st];
      if (o > red[threadIdx.x]) red[threadIdx.x] = o;
    }
    __syncthreads();
  }
  if (threadIdx.x == 0) atomicMax(best + b, red[0]);
}

// K10: fill output with 1e-5
__global__ void fill_k(float* __restrict__ out) {
  size_t i = (size_t)blockIdx.x * 256 + threadIdx.x;
  out[i] = 1e-5f;
}

// K11: write the winner
__global__ void win_k(const u64* __restrict__ best, const uint2* __restrict__ sp,
                      float* __restrict__ out) {
  int b = threadIdx.x;
  if (b >= NB) return;
  u64 pk = best[b];
  uint32_t j = 0xFFFFFFFFu - (uint32_t)(pk & 0xFFFFFFFFull);
  uint32_t tok = sp[(size_t)b * NV + j].y;
  out[(size_t)b * NV + tok] = 100000.0f;
}

// ---------------------------------------------------------------------------

extern "C" void kernel_launch(void* const* d_in, const int* in_sizes, int n_in,
                              void* d_out, int out_size, void* d_ws, size_t ws_size,
                              hipStream_t stream) {
  const int* ids = (const int*)d_in[0];
  const float* logits = (const float*)d_in[1];
  float* out = (float*)d_out;
  int T = in_sizes[0] / NB;   // 2048

  char* w = (char*)d_ws;
  // Time-aliased layout (73.8 MB total, < round-1-proven 74.16 MB):
  uint2*    pairsA = (uint2*)(w + 0);             // 32,768,000 B
  uint2*    pairsB = (uint2*)(w + 32768000);      // 32,768,000 B
  uint16_t* mask   = (uint16_t*)(w + 65536000);   //  8,192,000 B
  u64*      bins   = (u64*)(w + 0);               // alias pairsA: 16,777,216 B (dead before final_k)
  uint32_t* cnt    = (uint32_t*)(w + 65536000);   // alias mask:    4,096,000 B (mask dead after final_k)
  char* sm = w + 73728000;
  float*    pmax = (float*)(sm + 0);              // 16,000
  float*    mx   = (float*)(sm + 16000);          //    128
  float*    zf   = (float*)(sm + 16128);          //    128
  float*    gm   = (float*)(sm + 16256);          //  2,048
  double*   csum = (double*)(sm + 18304);         // 32,000
  uint32_t* cut  = (uint32_t*)(sm + 50304);       //    128
  u64*      best = (u64*)(sm + 50432);            //    256
  uint32_t* kd   = (uint32_t*)(sm + 50688);       //  4,096
  uint32_t* sk   = (uint32_t*)(sm + 54784);       //    256

  const int BVBLK = NB * (NV / 256);   // 16,000

  hipMemsetAsync(bins, 0, (size_t)NB * 65536 * sizeof(u64), stream);
  keys_k<<<1, 64, 0, stream>>>(ids, T, kd, sk, best);
  gmask_k<<<BVBLK, 256, 0, stream>>>(kd, mask);
  maxr1_k<<<NB * NBLK, 256, 0, stream>>>(logits, pmax);
  maxr2_k<<<1, 1024, 0, stream>>>(pmax, mx);
  expacc_k<<<BVBLK, 256, 0, stream>>>(logits, mask, mx, bins);
  fac_k<<<NB, 1024, 0, stream>>>(bins, zf, gm);
  final_k<<<BVBLK, 256, 0, stream>>>(logits, mask, mx, zf, gm, pairsA);

  // 4-pass LSD radix: A->B->A->B->A (ends in pairsA)
  const uint2* srcs[4] = { pairsA, pairsB, pairsA, pairsB };
  uint2*       dsts[4] = { pairsB, pairsA, pairsB, pairsA };
  for (int pass = 0; pass < 4; ++pass) {
    int shift = pass * 8;
    rhist_k<<<NB * NBLK, 256, 0, stream>>>(srcs[pass], cnt, shift);
    rscan_k<<<NB, 1024, 0, stream>>>(cnt);
    rscatter_k<<<NB * NBLK, 256, 0, stream>>>(srcs[pass], dsts[pass], cnt, shift);
  }

  chunks_k<<<NB * NCHUNK, 256, 0, stream>>>(pairsA, csum);
  cutoff_k<<<1, 32, 0, stream>>>(pairsA, csum, cut);
  argmax_k<<<NB * 16, 256, 0, stream>>>(pairsA, cut, sk, best);
  fill_k<<<BVBLK, 256, 0, stream>>>(out);
  win_k<<<1, 32, 0, stream>>>(best, pairsA, out);
}

// Round 3
// 783.160 us; speedup vs baseline: 4.8112x; 1.2724x over previous
//
#include <hip/hip_runtime.h>
#include <stdint.h>

// ============================================================================
// SynthID watermark processor — round 3: head-partitioned sort + parallel
// cutoff. RNG: jax_threefry_partitionable=True (validated r1/r2).
// Pipeline: keys -> gmask(+blockmax) -> max -> expacc(65536 group bins,u64)
//   -> fac (gm[16], Z) -> final (keys + 512-exp-bin mass/count histos)
//   -> binsel (head threshold covering 0.9f mass, +2-bin margin)
//   -> deterministic head compaction (count/scan/scatter, index-stable)
//   -> 4-pass LSD radix on head only -> chunk sums -> parallel cutoff
//   -> gumbel argmax -> scores.
// ============================================================================

#define NB 32
#define NV 128000
#define NDEPTH 16
#define NTB 500        // 256-token blocks per batch
#define NBINS 512      // exponent bins = key >> 23
#define CAP 96256      // head capacity per batch (94*1024)
#define NBLKH 94       // head radix blocks (1024 elems each) per batch
#define FPSCALE 17592186044416.0          // 2^44 (group bins)
#define MSCALE 1.152921504606846976e18    // 2^60 (bin mass)

typedef unsigned long long u64;

__device__ __forceinline__ uint32_t rotl32(uint32_t v, int r) {
  return (v << r) | (v >> (32 - r));
}

__device__ __forceinline__ void tf2x32(uint32_t k0, uint32_t k1,
                                       uint32_t x0, uint32_t x1,
                                       uint32_t &o0, uint32_t &o1) {
  uint32_t ks2 = k0 ^ k1 ^ 0x1BD11BDAu;
  x0 += k0; x1 += k1;
  x0 += x1; x1 = rotl32(x1, 13); x1 ^= x0;
  x0 += x1; x1 = rotl32(x1, 15); x1 ^= x0;
  x0 += x1; x1 = rotl32(x1, 26); x1 ^= x0;
  x0 += x1; x1 = rotl32(x1,  6); x1 ^= x0;
  x0 += k1; x1 += ks2 + 1u;
  x0 += x1; x1 = rotl32(x1, 17); x1 ^= x0;
  x0 += x1; x1 = rotl32(x1, 29); x1 ^= x0;
  x0 += x1; x1 = rotl32(x1, 16); x1 ^= x0;
  x0 += x1; x1 = rotl32(x1, 24); x1 ^= x0;
  x0 += ks2; x1 += k0 + 2u;
  x0 += x1; x1 = rotl32(x1, 13); x1 ^= x0;
  x0 += x1; x1 = rotl32(x1, 15); x1 ^= x0;
  x0 += x1; x1 = rotl32(x1, 26); x1 ^= x0;
  x0 += x1; x1 = rotl32(x1,  6); x1 ^= x0;
  x0 += k0; x1 += k1 + 3u;
  x0 += x1; x1 = rotl32(x1, 17); x1 ^= x0;
  x0 += x1; x1 = rotl32(x1, 29); x1 ^= x0;
  x0 += x1; x1 = rotl32(x1, 16); x1 ^= x0;
  x0 += x1; x1 = rotl32(x1, 24); x1 ^= x0;
  x0 += k1; x1 += ks2 + 4u;
  x0 += x1; x1 = rotl32(x1, 13); x1 ^= x0;
  x0 += x1; x1 = rotl32(x1, 15); x1 ^= x0;
  x0 += x1; x1 = rotl32(x1, 26); x1 ^= x0;
  x0 += x1; x1 = rotl32(x1,  6); x1 ^= x0;
  x0 += ks2; x1 += k0 + 5u;
  o0 = x0; o1 = x1;
}

__device__ __forceinline__ uint32_t random_bits32(uint32_t k0, uint32_t k1, uint32_t i) {
  uint32_t y0, y1;
  tf2x32(k0, k1, 0u, i, y0, y1);
  return y0 ^ y1;
}

// ---------------------------------------------------------------------------
__global__ void keys_k(const int* __restrict__ ids, int T,
                       uint32_t* __restrict__ kd, uint32_t* __restrict__ sk,
                       u64* __restrict__ best) {
  int t = threadIdx.x;
  if (t >= NB) return;
  uint32_t prior = 0;
  for (int q = 0; q < 4; ++q) prior += (uint32_t)ids[(size_t)t * T + (T - 4) + q];
  uint32_t b0, b1;
  tf2x32(0u, 0u, 0u, prior, b0, b1);
  for (int d = 0; d < NDEPTH; ++d) {
    uint32_t y0, y1;
    tf2x32(b0, b1, 0u, (uint32_t)d, y0, y1);
    kd[(t * NDEPTH + d) * 2 + 0] = y0;
    kd[(t * NDEPTH + d) * 2 + 1] = y1;
  }
  uint32_t s0, s1;
  tf2x32(0u, 1u, 0u, (uint32_t)t, s0, s1);
  sk[2 * t + 0] = s0;
  sk[2 * t + 1] = s1;
  best[t] = 0ull;
}

// gmask + per-256-token block max of logits
__global__ void gmaskmax_k(const uint32_t* __restrict__ kd, const float* __restrict__ logits,
                           uint16_t* __restrict__ mask, float* __restrict__ pmax) {
  int blk = blockIdx.x, t = threadIdx.x;
  int b = blk / NTB, c = blk % NTB;
  int v = c * 256 + t;
  size_t i = (size_t)b * NV + v;
  __shared__ uint32_t lk[NDEPTH * 2];
  if (t < NDEPTH * 2) lk[t] = kd[b * NDEPTH * 2 + t];
  __syncthreads();
  uint32_t m = 0;
  for (int d = 0; d < NDEPTH; ++d) {
    uint32_t bits = random_bits32(lk[2 * d], lk[2 * d + 1], (uint32_t)v);
    m |= (((bits >> 31) == 0u) ? 1u : 0u) << d;
  }
  mask[i] = (uint16_t)m;
  float x = logits[i];
  __shared__ float red[256];
  red[t] = x; __syncthreads();
  for (int s = 128; s > 0; s >>= 1) { if (t < s) red[t] = fmaxf(red[t], red[t + s]); __syncthreads(); }
  if (t == 0) pmax[b * NTB + c] = red[0];
}

__global__ void maxr2_k(const float* __restrict__ pmax, float* __restrict__ mx) {
  int t = threadIdx.x;
  int b = t >> 5, k = t & 31;
  float m = -3.4e38f;
  for (int i = k; i < NTB; i += 32) m = fmaxf(m, pmax[b * NTB + i]);
  for (int o = 16; o > 0; o >>= 1) m = fmaxf(m, __shfl_xor(m, o, 32));
  if (k == 0) mx[b] = m;
}

__global__ void expacc_k(const float* __restrict__ logits, const uint16_t* __restrict__ mask,
                         const float* __restrict__ mx, u64* __restrict__ bins) {
  size_t i = (size_t)blockIdx.x * 256 + threadIdx.x;
  int b = blockIdx.x / NTB;
  float e = expf(logits[i] - mx[b]);
  u64 q = (u64)((double)e * FPSCALE);
  atomicAdd(&bins[((size_t)b << 16) | mask[i]], q);
}

__launch_bounds__(1024)
__global__ void fac_k(const u64* __restrict__ bins, float* __restrict__ zf,
                      float* __restrict__ gm) {
  int b = blockIdx.x, t = threadIdx.x;
  int w = t >> 6, lane = t & 63;
  const u64* bb = bins + ((size_t)b << 16);
  u64 zp = 0;
  #pragma unroll
  for (int j = 0; j < 64; ++j) zp += bb[t * 64 + j];
  for (int o = 32; o > 0; o >>= 1) zp += __shfl_xor(zp, o);
  __shared__ u64 zw[16];
  if (lane == 0) zw[w] = zp;
  __syncthreads();
  __shared__ double Zsh;
  if (t == 0) {
    u64 zi = 0;
    for (int k = 0; k < 16; ++k) zi += zw[k];
    Zsh = (double)zi * (1.0 / FPSCALE);
  }
  __syncthreads();
  double Zd = Zsh;
  if (t == 0) zf[b] = (float)Zd;
  float cur[64];
  #pragma unroll
  for (int j = 0; j < 64; ++j)
    cur[j] = (float)((double)bb[t * 64 + j] * (1.0 / FPSCALE) / Zd);
  __shared__ double gw[16];
  __shared__ double gsh;
  for (int d = 0; d < NDEPTH; ++d) {
    double part = 0.0;
    #pragma unroll
    for (int j = 0; j < 64; ++j) {
      int m = (t << 6) | j;
      if ((m >> d) & 1) part += (double)cur[j];
    }
    for (int o = 32; o > 0; o >>= 1) part += __shfl_xor(part, o);
    if (lane == 0) gw[w] = part;
    __syncthreads();
    if (t == 0) {
      double s = 0.0;
      for (int k = 0; k < 16; ++k) s += gw[k];
      gsh = s;
    }
    __syncthreads();
    float g = (float)gsh;
    if (t == 0) gm[b * NDEPTH + d] = g;
    #pragma unroll
    for (int j = 0; j < 64; ++j) {
      int m = (t << 6) | j;
      float f = (1.0f + (float)((m >> d) & 1)) - g;
      cur[j] *= f;
    }
    __syncthreads();
  }
}

// final p (exact r2 arithmetic) -> key array + 512-bin mass/count histograms
__global__ void final_k(const float* __restrict__ logits, const uint16_t* __restrict__ mask,
                        const float* __restrict__ mx, const float* __restrict__ zf,
                        const float* __restrict__ gm, uint32_t* __restrict__ keys,
                        u64* __restrict__ binmass, uint32_t* __restrict__ bincnt) {
  int b = blockIdx.x / NTB;
  int t = threadIdx.x;
  __shared__ float gsh[NDEPTH];
  __shared__ float msh, zsh;
  __shared__ u64 bm[NBINS];
  __shared__ uint32_t bc[NBINS];
  if (t < NDEPTH) gsh[t] = gm[b * NDEPTH + t];
  if (t == 16) msh = mx[b];
  if (t == 17) zsh = zf[b];
  for (int i = t; i < NBINS; i += 256) { bm[i] = 0ull; bc[i] = 0u; }
  __syncthreads();
  size_t i = (size_t)blockIdx.x * 256 + t;
  float p = expf(logits[i] - msh) / zsh;
  uint16_t mk = mask[i];
  #pragma unroll
  for (int d = 0; d < NDEPTH; ++d) {
    float g = (float)((mk >> d) & 1);
    p = p * ((1.0f + g) - gsh[d]);
  }
  uint32_t key = ~__float_as_uint(p);
  keys[i] = key;
  uint32_t bin = key >> 23;
  atomicAdd(&bm[bin], (u64)((double)p * MSCALE));
  atomicAdd(&bc[bin], 1u);
  __syncthreads();
  for (int k = t; k < NBINS; k += 256) {
    if (bc[k]) atomicAdd(&bincnt[b * NBINS + k], bc[k]);
    if (bm[k]) atomicAdd(&binmass[b * NBINS + k], bm[k]);
  }
}

// pick head threshold: first bin crossing absolute 0.9f mass, +2 bins margin
__launch_bounds__(512)
__global__ void binsel_k(const u64* __restrict__ binmass, const uint32_t* __restrict__ bincnt,
                         uint32_t* __restrict__ Kthr, uint32_t* __restrict__ Hlen) {
  int b = blockIdx.x, t = threadIdx.x;
  __shared__ u64 cm[NBINS];
  __shared__ uint32_t cc[NBINS];
  __shared__ int selB;
  cm[t] = binmass[b * NBINS + t];
  cc[t] = bincnt[b * NBINS + t];
  if (t == 0) selB = NBINS - 3;
  __syncthreads();
  for (int off = 1; off < NBINS; off <<= 1) {
    u64 a = (t >= off) ? cm[t - off] : 0ull;
    uint32_t d = (t >= off) ? cc[t - off] : 0u;
    __syncthreads();
    cm[t] += a; cc[t] += d;
    __syncthreads();
  }
  const u64 thr = (u64)((double)0.9f * MSCALE);
  if (cm[t] >= thr && (t == 0 || cm[t - 1] < thr)) atomicMin(&selB, t);
  __syncthreads();
  if (t == 0) {
    int Bs = selB + 2;
    if (Bs > NBINS - 1) Bs = NBINS - 1;
    while (Bs > 0 && cc[Bs] > CAP) --Bs;
    u64 kt = (((u64)(Bs + 1)) << 23) - 1ull;
    Kthr[b] = (uint32_t)kt;
    Hlen[b] = cc[Bs];
  }
}

// per-256-chunk head-element counts
__global__ void hcount_k(const uint32_t* __restrict__ keys, const uint32_t* __restrict__ Kthr,
                         uint32_t* __restrict__ hcnt) {
  int blk = blockIdx.x, t = threadIdx.x;
  int b = blk / NTB, c = blk % NTB;
  size_t i = (size_t)blk * 256 + t;
  bool active = keys[i] <= Kthr[b];
  u64 am = __ballot(active);
  __shared__ uint32_t wc[4];
  if ((t & 63) == 0) wc[t >> 6] = (uint32_t)__popcll(am);
  __syncthreads();
  if (t == 0) hcnt[b * NTB + c] = wc[0] + wc[1] + wc[2] + wc[3];
}

// exclusive scan of the 500 per-chunk counts (in place)
__launch_bounds__(1024)
__global__ void hscan_k(uint32_t* __restrict__ hcnt) {
  int b = blockIdx.x, t = threadIdx.x;
  uint32_t v = (t < NTB) ? hcnt[b * NTB + t] : 0u;
  __shared__ uint32_t sc[1024];
  sc[t] = v;
  __syncthreads();
  for (int off = 1; off < 1024; off <<= 1) {
    uint32_t a = (t >= off) ? sc[t - off] : 0u;
    __syncthreads();
    sc[t] += a;
    __syncthreads();
  }
  if (t < NTB) hcnt[b * NTB + t] = sc[t] - v;
}

// deterministic index-ordered compaction into head pairs
__global__ void hcompact_k(const uint32_t* __restrict__ keys, const uint32_t* __restrict__ Kthr,
                           const uint32_t* __restrict__ hcnt, uint2* __restrict__ headA) {
  int blk = blockIdx.x, t = threadIdx.x;
  int b = blk / NTB, c = blk % NTB;
  int v = c * 256 + t;
  size_t i = (size_t)blk * 256 + t;
  uint32_t key = keys[i];
  bool active = key <= Kthr[b];
  int w = t >> 6, lane = t & 63;
  u64 am = __ballot(active);
  uint32_t rank = (uint32_t)__popcll(am & ((1ull << lane) - 1ull));
  __shared__ uint32_t wc[4];
  if ((t & 63) == 0) wc[t >> 6] = (uint32_t)__popcll(am);
  __syncthreads();
  uint32_t off = hcnt[b * NTB + c] + rank;
  for (int w2 = 0; w2 < w; ++w2) off += wc[w2];
  if (active) headA[(size_t)b * CAP + off] = make_uint2(key, (uint32_t)v);
}

// ---------------- head radix: 4 passes x 8 bits ----------------------------
__global__ void rhist_k(const uint2* __restrict__ src, const uint32_t* __restrict__ Hlen,
                        uint32_t* __restrict__ cnt, int shift) {
  int blk = blockIdx.x, t = threadIdx.x;
  int b = blk / NBLKH, c = blk % NBLKH;
  uint32_t H = Hlen[b];
  const uint2* s = src + (size_t)b * CAP + (size_t)c * 1024;
  __shared__ uint32_t lh[256];
  lh[t] = 0;
  __syncthreads();
  #pragma unroll
  for (int e = 0; e < 4; ++e) {
    uint32_t idx = (uint32_t)(c * 1024 + 256 * e + t);
    if (idx < H) atomicAdd(&lh[(s[t + 256 * e].x >> shift) & 255u], 1u);
  }
  __syncthreads();
  cnt[((size_t)b * 256 + t) * NBLKH + c] = lh[t];
}

__launch_bounds__(1024)
__global__ void rscan_k(uint32_t* __restrict__ cnt) {
  const int NE = 256 * NBLKH;   // 24064
  const int NL = 24;
  int b = blockIdx.x, t = threadIdx.x;
  uint32_t* cc = cnt + (size_t)b * NE;
  uint32_t loc[NL];
  uint32_t s = 0;
  int base = t * NL;
  #pragma unroll
  for (int j = 0; j < NL; ++j) {
    loc[j] = (base + j < NE) ? cc[base + j] : 0u;
    s += loc[j];
  }
  __shared__ uint32_t sc[1024];
  sc[t] = s;
  __syncthreads();
  for (int off = 1; off < 1024; off <<= 1) {
    uint32_t v = (t >= off) ? sc[t - off] : 0u;
    __syncthreads();
    sc[t] += v;
    __syncthreads();
  }
  uint32_t run = sc[t] - s;
  #pragma unroll
  for (int j = 0; j < NL; ++j) {
    if (base + j < NE) { uint32_t o = loc[j]; cc[base + j] = run; run += o; }
  }
}

__launch_bounds__(256)
__global__ void rscatter_k(const uint2* __restrict__ src, uint2* __restrict__ dst,
                           const uint32_t* __restrict__ Hlen,
                           const uint32_t* __restrict__ cnt, int shift) {
  int blk = blockIdx.x, t = threadIdx.x;
  int b = blk / NBLKH, c = blk % NBLKH;
  uint32_t H = Hlen[b];
  const uint2* s = src + (size_t)b * CAP + (size_t)c * 1024;
  uint2* d = dst + (size_t)b * CAP;
  int w = t >> 6, lane = t & 63;
  __shared__ uint32_t runb[256];
  __shared__ uint32_t wvc[4][256];
  runb[t] = cnt[((size_t)b * 256 + t) * NBLKH + c];
  uint2 el[4];
  #pragma unroll
  for (int e = 0; e < 4; ++e) el[e] = s[t + 256 * e];
  u64 lowmask = (1ull << lane) - 1ull;
  #pragma unroll
  for (int e = 0; e < 4; ++e) {
    uint32_t* wf = &wvc[0][0];
    wf[t] = 0; wf[t + 256] = 0; wf[t + 512] = 0; wf[t + 768] = 0;
    __syncthreads();
    bool active = (uint32_t)(c * 1024 + 256 * e + t) < H;
    uint32_t dig = active ? ((el[e].x >> shift) & 255u) : 0u;
    u64 act = __ballot(active);
    u64 m = ~0ull;
    #pragma unroll
    for (int bit = 0; bit < 8; ++bit) {
      u64 bb = __ballot((dig >> bit) & 1u);
      m &= ((dig >> bit) & 1u) ? bb : ~bb;
    }
    m &= act;
    uint32_t rank = (uint32_t)__popcll(m & lowmask);
    if (active && rank == 0) wvc[w][dig] = (uint32_t)__popcll(m);
    __syncthreads();
    if (active) {
      uint32_t off = runb[dig] + rank;
      for (int w2 = 0; w2 < w; ++w2) off += wvc[w2][dig];
      d[off] = el[e];
    }
    __syncthreads();
    runb[t] += wvc[0][t] + wvc[1][t] + wvc[2][t] + wvc[3][t];
    __syncthreads();
  }
}

// ---------------------------------------------------------------------------
__global__ void chunks_k(const uint2* __restrict__ sp, const uint32_t* __restrict__ Hlen,
                         double* __restrict__ cs) {
  int blk = blockIdx.x, t = threadIdx.x;
  int b = blk / NBLKH, c = blk % NBLKH;
  uint32_t H = Hlen[b];
  const uint2* p = sp + (size_t)b * CAP + (size_t)c * 1024;
  double s = 0.0;
  for (int k = t; k < 1024; k += 256) {
    uint32_t idx = (uint32_t)(c * 1024 + k);
    if (idx < H) s += (double)__uint_as_float(~p[k].x);
  }
  __shared__ double red[256];
  red[t] = s; __syncthreads();
  for (int st = 128; st > 0; st >>= 1) {
    if (t < st) red[t] += red[t + st];
    __syncthreads();
  }
  if (t == 0) cs[b * NBLKH + c] = red[0];
}

// parallel cutoff: f64 chunk-scan + in-chunk f64 scan
__launch_bounds__(1024)
__global__ void cutoff_k(const uint2* __restrict__ sp, const double* __restrict__ cs,
                         const uint32_t* __restrict__ Hlen, uint32_t* __restrict__ cut) {
  int b = blockIdx.x, t = threadIdx.x;
  const double TOPP = (double)0.9f;
  uint32_t H = Hlen[b];
  __shared__ double scd[1024];
  __shared__ int chSel;
  __shared__ double baseSel;
  if (t == 0) { chSel = -1; baseSel = 0.0; }
  double v = (t < NBLKH) ? cs[b * NBLKH + t] : 0.0;
  scd[t] = v;
  __syncthreads();
  for (int off = 1; off < 1024; off <<= 1) {
    double a = (t >= off) ? scd[t - off] : 0.0;
    __syncthreads();
    scd[t] += a;
    __syncthreads();
  }
  if (t < NBLKH && scd[t] >= TOPP && (t == 0 || scd[t - 1] < TOPP)) {
    chSel = t;
    baseSel = (t == 0) ? 0.0 : scd[t - 1];
  }
  __syncthreads();
  int CH = chSel;
  if (CH < 0) { if (t == 0) cut[b] = H - 1; return; }
  double base = baseSel;
  uint32_t idx = (uint32_t)(CH * 1024 + t);
  double pv = (idx < H) ? (double)__uint_as_float(~sp[(size_t)b * CAP + idx].x) : 0.0;
  __syncthreads();
  scd[t] = pv;
  __syncthreads();
  for (int off = 1; off < 1024; off <<= 1) {
    double a = (t >= off) ? scd[t - off] : 0.0;
    __syncthreads();
    scd[t] += a;
    __syncthreads();
  }
  __shared__ int kSel;
  if (t == 0) kSel = 1023;
  __syncthreads();
  if (base + scd[t] >= TOPP && (t == 0 || base + scd[t - 1] < TOPP)) kSel = t;
  __syncthreads();
  if (t == 0) cut[b] = (uint32_t)(CH * 1024 + kSel);
}

__global__ void argmax_k(const uint2* __restrict__ sp, const uint32_t* __restrict__ cut,
                         const uint32_t* __restrict__ sk, u64* __restrict__ best) {
  const int SUB = 16;
  int b = blockIdx.x / SUB;
  int s = blockIdx.x % SUB;
  uint32_t c = cut[b];
  uint32_t k0 = sk[2 * b], k1 = sk[2 * b + 1];
  u64 loc = 0ull;
  for (uint32_t j = (uint32_t)(s * 256 + threadIdx.x); j <= c; j += SUB * 256) {
    uint32_t bits = random_bits32(k0, k1, j);
    uint32_t m = bits >> 9;
    float u = (m == 0u) ? 1.17549435e-38f : (float)m * 1.1920928955078125e-7f;
    float gum = -logf(-logf(u));
    float scv = logf(__uint_as_float(~sp[(size_t)b * CAP + j].x)) + gum;
    uint32_t su = __float_as_uint(scv);
    uint32_t ord = (su & 0x80000000u) ? ~su : (su | 0x80000000u);
    u64 pk = ((u64)ord << 32) | (u64)(0xFFFFFFFFu - j);
    loc = (pk > loc) ? pk : loc;
  }
  __shared__ u64 red[256];
  red[threadIdx.x] = loc;
  __syncthreads();
  for (int st = 128; st > 0; st >>= 1) {
    if (threadIdx.x < st) {
      u64 o = red[threadIdx.x + st];
      if (o > red[threadIdx.x]) red[threadIdx.x] = o;
    }
    __syncthreads();
  }
  if (threadIdx.x == 0) atomicMax(best + b, red[0]);
}

__global__ void fill_k(float* __restrict__ out) {
  size_t i = (size_t)blockIdx.x * 256 + threadIdx.x;
  out[i] = 1e-5f;
}

__global__ void win_k(const u64* __restrict__ best, const uint2* __restrict__ sp,
                      float* __restrict__ out) {
  int b = threadIdx.x;
  if (b >= NB) return;
  u64 pk = best[b];
  uint32_t j = 0xFFFFFFFFu - (uint32_t)(pk & 0xFFFFFFFFull);
  uint32_t tok = sp[(size_t)b * CAP + j].y;
  out[(size_t)b * NV + tok] = 100000.0f;
}

// ---------------------------------------------------------------------------
extern "C" void kernel_launch(void* const* d_in, const int* in_sizes, int n_in,
                              void* d_out, int out_size, void* d_ws, size_t ws_size,
                              hipStream_t stream) {
  const int* ids = (const int*)d_in[0];
  const float* logits = (const float*)d_in[1];
  float* out = (float*)d_out;
  int T = in_sizes[0] / NB;

  char* w = (char*)d_ws;
  // headA/headB: 32*96256*8 = 24,641,536 each
  uint2*    headA = (uint2*)(w + 0);
  uint2*    headB = (uint2*)(w + 24641536);
  uint16_t* mask  = (uint16_t*)(w + 49283072);        // 8,192,000
  // aliases:
  u64*      bins  = (u64*)(w + 0);                    // 16,777,216 (dead before hcompact)
  uint32_t* keys  = (uint32_t*)(w + 24641536);        // 16,384,000 in headB (dead before radix pass1)
  uint32_t* cnt   = (uint32_t*)(w + 49283072);        // 3,080,192 in mask region (after final)
  double*   csum  = (double*)(w + 52400000);          // 24,064 in mask region
  uint32_t* cut   = (uint32_t*)(w + 52430080);        // 128 in mask region
  // non-aliased smalls:
  char* S = w + 57475072;
  float*    pmax    = (float*)(S + 0);                // 64,000
  uint32_t* hcnt    = (uint32_t*)(S + 64000);         // 64,000
  float*    mx      = (float*)(S + 128000);           // 128
  float*    zf      = (float*)(S + 128128);           // 128
  float*    gm      = (float*)(S + 128256);           // 2,048
  uint32_t* kd      = (uint32_t*)(S + 130304);        // 4,096
  uint32_t* sk      = (uint32_t*)(S + 134400);        // 256
  u64*      best    = (u64*)(S + 134656);             // 256
  uint32_t* Kthr    = (uint32_t*)(S + 134912);        // 128
  uint32_t* Hlen    = (uint32_t*)(S + 135040);        // 128
  u64*      binmass = (u64*)(S + 135168);             // 131,072
  uint32_t* bincnt  = (uint32_t*)(S + 266240);        // 65,536
  // total: 57,475,072 + 331,776 = 57,806,848 bytes

  hipMemsetAsync(bins, 0, (size_t)NB * 65536 * sizeof(u64), stream);
  hipMemsetAsync(binmass, 0, 131072 + 65536, stream);

  keys_k<<<1, 64, 0, stream>>>(ids, T, kd, sk, best);
  gmaskmax_k<<<NB * NTB, 256, 0, stream>>>(kd, logits, mask, pmax);
  maxr2_k<<<1, 1024, 0, stream>>>(pmax, mx);
  expacc_k<<<NB * NTB, 256, 0, stream>>>(logits, mask, mx, bins);
  fac_k<<<NB, 1024, 0, stream>>>(bins, zf, gm);
  final_k<<<NB * NTB, 256, 0, stream>>>(logits, mask, mx, zf, gm, keys, binmass, bincnt);
  binsel_k<<<NB, NBINS, 0, stream>>>(binmass, bincnt, Kthr, Hlen);
  hcount_k<<<NB * NTB, 256, 0, stream>>>(keys, Kthr, hcnt);
  hscan_k<<<NB, 1024, 0, stream>>>(hcnt);
  hcompact_k<<<NB * NTB, 256, 0, stream>>>(keys, Kthr, hcnt, headA);

  const uint2* srcs[4] = { headA, headB, headA, headB };
  uint2*       dsts[4] = { headB, headA, headB, headA };
  for (int pass = 0; pass < 4; ++pass) {
    int shift = pass * 8;
    rhist_k<<<NB * NBLKH, 256, 0, stream>>>(srcs[pass], Hlen, cnt, shift);
    rscan_k<<<NB, 1024, 0, stream>>>(cnt);
    rscatter_k<<<NB * NBLKH, 256, 0, stream>>>(srcs[pass], dsts[pass], Hlen, cnt, shift);
  }

  chunks_k<<<NB * NBLKH, 256, 0, stream>>>(headA, Hlen, csum);
  cutoff_k<<<NB, 1024, 0, stream>>>(headA, csum, Hlen, cut);
  argmax_k<<<NB * 16, 256, 0, stream>>>(headA, cut, sk, best);
  fill_k<<<NB * NTB, 256, 0, stream>>>(out);
  win_k<<<1, 32, 0, stream>>>(best, headA, out);
}

// Round 4
// 552.128 us; speedup vs baseline: 6.8245x; 1.4184x over previous
//
#include <hip/hip_runtime.h>
#include <stdint.h>

// ============================================================================
// SynthID watermark processor — round 4: factorized gm computation (no 65536
// global bins, no device-atomic storm), head-partitioned radix sort.
// RNG: jax_threefry_partitionable=True (validated r1-r3).
// gm factorization: weight product Π w_d splits into W_lo(mask&255)*W_hi(mask>>8):
//   lohist(256-bin LDS histo) -> faclo(depths 0-7 + W_lo table)
//   -> hihist(p0*W_lo into 256 hi-bins) -> fachi(depths 8-15).
// Downstream (final/binsel/compact/radix/cutoff/argmax) identical to r3.
// ============================================================================

#define NB 32
#define NV 128000
#define NDEPTH 16
#define NTB 500        // 256-token blocks per batch
#define NBINS 512      // exponent bins = key >> 23
#define CAP 96256      // head capacity per batch (94*1024)
#define NBLKH 94       // head radix blocks (1024 elems each) per batch
#define FPSCALE 17592186044416.0          // 2^44 (p0 fixed point)
#define TSCALE  68719476736.0             // 2^36 (weighted mass fixed point)
#define MSCALE 1.152921504606846976e18    // 2^60 (bin mass)

typedef unsigned long long u64;

__device__ __forceinline__ uint32_t rotl32(uint32_t v, int r) {
  return (v << r) | (v >> (32 - r));
}

__device__ __forceinline__ void tf2x32(uint32_t k0, uint32_t k1,
                                       uint32_t x0, uint32_t x1,
                                       uint32_t &o0, uint32_t &o1) {
  uint32_t ks2 = k0 ^ k1 ^ 0x1BD11BDAu;
  x0 += k0; x1 += k1;
  x0 += x1; x1 = rotl32(x1, 13); x1 ^= x0;
  x0 += x1; x1 = rotl32(x1, 15); x1 ^= x0;
  x0 += x1; x1 = rotl32(x1, 26); x1 ^= x0;
  x0 += x1; x1 = rotl32(x1,  6); x1 ^= x0;
  x0 += k1; x1 += ks2 + 1u;
  x0 += x1; x1 = rotl32(x1, 17); x1 ^= x0;
  x0 += x1; x1 = rotl32(x1, 29); x1 ^= x0;
  x0 += x1; x1 = rotl32(x1, 16); x1 ^= x0;
  x0 += x1; x1 = rotl32(x1, 24); x1 ^= x0;
  x0 += ks2; x1 += k0 + 2u;
  x0 += x1; x1 = rotl32(x1, 13); x1 ^= x0;
  x0 += x1; x1 = rotl32(x1, 15); x1 ^= x0;
  x0 += x1; x1 = rotl32(x1, 26); x1 ^= x0;
  x0 += x1; x1 = rotl32(x1,  6); x1 ^= x0;
  x0 += k0; x1 += k1 + 3u;
  x0 += x1; x1 = rotl32(x1, 17); x1 ^= x0;
  x0 += x1; x1 = rotl32(x1, 29); x1 ^= x0;
  x0 += x1; x1 = rotl32(x1, 16); x1 ^= x0;
  x0 += x1; x1 = rotl32(x1, 24); x1 ^= x0;
  x0 += k1; x1 += ks2 + 4u;
  x0 += x1; x1 = rotl32(x1, 13); x1 ^= x0;
  x0 += x1; x1 = rotl32(x1, 15); x1 ^= x0;
  x0 += x1; x1 = rotl32(x1, 26); x1 ^= x0;
  x0 += x1; x1 = rotl32(x1,  6); x1 ^= x0;
  x0 += ks2; x1 += k0 + 5u;
  o0 = x0; o1 = x1;
}

__device__ __forceinline__ uint32_t random_bits32(uint32_t k0, uint32_t k1, uint32_t i) {
  uint32_t y0, y1;
  tf2x32(k0, k1, 0u, i, y0, y1);
  return y0 ^ y1;
}

// ---------------------------------------------------------------------------
__global__ void keys_k(const int* __restrict__ ids, int T,
                       uint32_t* __restrict__ kd, uint32_t* __restrict__ sk,
                       u64* __restrict__ best) {
  int t = threadIdx.x;
  if (t >= NB) return;
  uint32_t prior = 0;
  for (int q = 0; q < 4; ++q) prior += (uint32_t)ids[(size_t)t * T + (T - 4) + q];
  uint32_t b0, b1;
  tf2x32(0u, 0u, 0u, prior, b0, b1);
  for (int d = 0; d < NDEPTH; ++d) {
    uint32_t y0, y1;
    tf2x32(b0, b1, 0u, (uint32_t)d, y0, y1);
    kd[(t * NDEPTH + d) * 2 + 0] = y0;
    kd[(t * NDEPTH + d) * 2 + 1] = y1;
  }
  uint32_t s0, s1;
  tf2x32(0u, 1u, 0u, (uint32_t)t, s0, s1);
  sk[2 * t + 0] = s0;
  sk[2 * t + 1] = s1;
  best[t] = 0ull;
}

// gmask + per-256-token block max of logits
__global__ void gmaskmax_k(const uint32_t* __restrict__ kd, const float* __restrict__ logits,
                           uint16_t* __restrict__ mask, float* __restrict__ pmax) {
  int blk = blockIdx.x, t = threadIdx.x;
  int b = blk / NTB, c = blk % NTB;
  int v = c * 256 + t;
  size_t i = (size_t)b * NV + v;
  __shared__ uint32_t lk[NDEPTH * 2];
  if (t < NDEPTH * 2) lk[t] = kd[b * NDEPTH * 2 + t];
  __syncthreads();
  uint32_t m = 0;
  for (int d = 0; d < NDEPTH; ++d) {
    uint32_t bits = random_bits32(lk[2 * d], lk[2 * d + 1], (uint32_t)v);
    m |= (((bits >> 31) == 0u) ? 1u : 0u) << d;
  }
  mask[i] = (uint16_t)m;
  float x = logits[i];
  __shared__ float red[256];
  red[t] = x; __syncthreads();
  for (int s = 128; s > 0; s >>= 1) { if (t < s) red[t] = fmaxf(red[t], red[t + s]); __syncthreads(); }
  if (t == 0) pmax[b * NTB + c] = red[0];
}

__global__ void maxr2_k(const float* __restrict__ pmax, float* __restrict__ mx) {
  int t = threadIdx.x;
  int b = t >> 5, k = t & 31;
  float m = -3.4e38f;
  for (int i = k; i < NTB; i += 32) m = fmaxf(m, pmax[b * NTB + i]);
  for (int o = 16; o > 0; o >>= 1) m = fmaxf(m, __shfl_xor(m, o, 32));
  if (k == 0) mx[b] = m;
}

// 256-bin low-byte histogram of fixed-point p0 (LDS-aggregated, deterministic)
__global__ void lohist_k(const float* __restrict__ logits, const uint16_t* __restrict__ mask,
                         const float* __restrict__ mx, u64* __restrict__ Hlo) {
  int blk = blockIdx.x, t = threadIdx.x;
  int b = blk / NTB;
  __shared__ u64 h[256];
  h[t] = 0ull;
  __syncthreads();
  size_t i = (size_t)blk * 256 + t;
  float e = expf(logits[i] - mx[b]);
  u64 q = (u64)((double)e * FPSCALE);
  atomicAdd(&h[mask[i] & 255u], q);
  __syncthreads();
  if (h[t]) atomicAdd(&Hlo[b * 256 + t], h[t]);
}

// depths 0..7 on the 256-entry low histogram; exact integer Z; emits W_lo table
__global__ void faclo_k(const u64* __restrict__ Hlo, u64* __restrict__ Zint,
                        float* __restrict__ zf, float* __restrict__ gm,
                        float* __restrict__ wloTab) {
  int b = blockIdx.x, t = threadIdx.x;
  u64 v = Hlo[b * 256 + t];
  __shared__ u64 zr[256];
  zr[t] = v; __syncthreads();
  for (int s = 128; s > 0; s >>= 1) { if (t < s) zr[t] += zr[t + s]; __syncthreads(); }
  __shared__ double Zsh;
  if (t == 0) {
    Zint[b] = zr[0];
    Zsh = (double)zr[0] * (1.0 / FPSCALE);
    zf[b] = (float)Zsh;
  }
  __syncthreads();
  double Zd = Zsh;
  float base = (float)((double)v * (1.0 / FPSCALE) / Zd);
  float w = 1.0f;
  __shared__ double dr[256];
  for (int d = 0; d < 8; ++d) {
    int bit = (t >> d) & 1;
    dr[t] = bit ? (double)(base * w) : 0.0;
    __syncthreads();
    for (int s = 128; s > 0; s >>= 1) { if (t < s) dr[t] += dr[t + s]; __syncthreads(); }
    float g = (float)dr[0];
    if (t == 0) gm[b * NDEPTH + d] = g;
    w *= (1.0f + (float)bit) - g;
    __syncthreads();
  }
  wloTab[b * 256 + t] = w;
}

// 256-bin high-byte histogram of p0 * W_lo(lo)  (fixed-point 2^36)
__global__ void hihist_k(const float* __restrict__ logits, const uint16_t* __restrict__ mask,
                         const float* __restrict__ mx, const float* __restrict__ wloTab,
                         u64* __restrict__ Thist) {
  int blk = blockIdx.x, t = threadIdx.x;
  int b = blk / NTB;
  __shared__ u64 h[256];
  __shared__ float wl[256];
  h[t] = 0ull;
  wl[t] = wloTab[b * 256 + t];
  __syncthreads();
  size_t i = (size_t)blk * 256 + t;
  float e = expf(logits[i] - mx[b]);
  uint32_t mk = mask[i];
  double prod = (double)e * (double)wl[mk & 255u];
  atomicAdd(&h[mk >> 8], (u64)(prod * TSCALE));
  __syncthreads();
  if (h[t]) atomicAdd(&Thist[b * 256 + t], h[t]);
}

// depths 8..15 on the 256-entry weighted high histogram
__global__ void fachi_k(const u64* __restrict__ Thist, const u64* __restrict__ Zint,
                        float* __restrict__ gm) {
  int b = blockIdx.x, t = threadIdx.x;
  double Zd = (double)Zint[b] * (1.0 / FPSCALE);
  u64 v = Thist[b * 256 + t];
  float base = (float)((double)v * (1.0 / TSCALE) / Zd);
  float w = 1.0f;
  __shared__ double dr[256];
  for (int d = 8; d < NDEPTH; ++d) {
    int bit = (t >> (d - 8)) & 1;
    dr[t] = bit ? (double)(base * w) : 0.0;
    __syncthreads();
    for (int s = 128; s > 0; s >>= 1) { if (t < s) dr[t] += dr[t + s]; __syncthreads(); }
    float g = (float)dr[0];
    if (t == 0) gm[b * NDEPTH + d] = g;
    w *= (1.0f + (float)bit) - g;
    __syncthreads();
  }
}

// final p (exact per-token chain) -> key array + 512-bin mass/count histograms
__global__ void final_k(const float* __restrict__ logits, const uint16_t* __restrict__ mask,
                        const float* __restrict__ mx, const float* __restrict__ zf,
                        const float* __restrict__ gm, uint32_t* __restrict__ keys,
                        u64* __restrict__ binmass, uint32_t* __restrict__ bincnt) {
  int b = blockIdx.x / NTB;
  int t = threadIdx.x;
  __shared__ float gsh[NDEPTH];
  __shared__ float msh, zsh;
  __shared__ u64 bm[NBINS];
  __shared__ uint32_t bc[NBINS];
  if (t < NDEPTH) gsh[t] = gm[b * NDEPTH + t];
  if (t == 16) msh = mx[b];
  if (t == 17) zsh = zf[b];
  for (int i = t; i < NBINS; i += 256) { bm[i] = 0ull; bc[i] = 0u; }
  __syncthreads();
  size_t i = (size_t)blockIdx.x * 256 + t;
  float p = expf(logits[i] - msh) / zsh;
  uint16_t mk = mask[i];
  #pragma unroll
  for (int d = 0; d < NDEPTH; ++d) {
    float g = (float)((mk >> d) & 1);
    p = p * ((1.0f + g) - gsh[d]);
  }
  uint32_t key = ~__float_as_uint(p);
  keys[i] = key;
  uint32_t bin = key >> 23;
  atomicAdd(&bm[bin], (u64)((double)p * MSCALE));
  atomicAdd(&bc[bin], 1u);
  __syncthreads();
  for (int k = t; k < NBINS; k += 256) {
    if (bc[k]) atomicAdd(&bincnt[b * NBINS + k], bc[k]);
    if (bm[k]) atomicAdd(&binmass[b * NBINS + k], bm[k]);
  }
}

// pick head threshold: first bin crossing absolute 0.9f mass, +2 bins margin
__launch_bounds__(512)
__global__ void binsel_k(const u64* __restrict__ binmass, const uint32_t* __restrict__ bincnt,
                         uint32_t* __restrict__ Kthr, uint32_t* __restrict__ Hlen) {
  int b = blockIdx.x, t = threadIdx.x;
  __shared__ u64 cm[NBINS];
  __shared__ uint32_t cc[NBINS];
  __shared__ int selB;
  cm[t] = binmass[b * NBINS + t];
  cc[t] = bincnt[b * NBINS + t];
  if (t == 0) selB = NBINS - 3;
  __syncthreads();
  for (int off = 1; off < NBINS; off <<= 1) {
    u64 a = (t >= off) ? cm[t - off] : 0ull;
    uint32_t d = (t >= off) ? cc[t - off] : 0u;
    __syncthreads();
    cm[t] += a; cc[t] += d;
    __syncthreads();
  }
  const u64 thr = (u64)((double)0.9f * MSCALE);
  if (cm[t] >= thr && (t == 0 || cm[t - 1] < thr)) atomicMin(&selB, t);
  __syncthreads();
  if (t == 0) {
    int Bs = selB + 2;
    if (Bs > NBINS - 1) Bs = NBINS - 1;
    while (Bs > 0 && cc[Bs] > CAP) --Bs;
    u64 kt = (((u64)(Bs + 1)) << 23) - 1ull;
    Kthr[b] = (uint32_t)kt;
    Hlen[b] = cc[Bs];
  }
}

// per-256-chunk head-element counts
__global__ void hcount_k(const uint32_t* __restrict__ keys, const uint32_t* __restrict__ Kthr,
                         uint32_t* __restrict__ hcnt) {
  int blk = blockIdx.x, t = threadIdx.x;
  int b = blk / NTB, c = blk % NTB;
  size_t i = (size_t)blk * 256 + t;
  bool active = keys[i] <= Kthr[b];
  u64 am = __ballot(active);
  __shared__ uint32_t wc[4];
  if ((t & 63) == 0) wc[t >> 6] = (uint32_t)__popcll(am);
  __syncthreads();
  if (t == 0) hcnt[b * NTB + c] = wc[0] + wc[1] + wc[2] + wc[3];
}

// exclusive scan of the 500 per-chunk counts (in place)
__launch_bounds__(1024)
__global__ void hscan_k(uint32_t* __restrict__ hcnt) {
  int b = blockIdx.x, t = threadIdx.x;
  uint32_t v = (t < NTB) ? hcnt[b * NTB + t] : 0u;
  __shared__ uint32_t sc[1024];
  sc[t] = v;
  __syncthreads();
  for (int off = 1; off < 1024; off <<= 1) {
    uint32_t a = (t >= off) ? sc[t - off] : 0u;
    __syncthreads();
    sc[t] += a;
    __syncthreads();
  }
  if (t < NTB) hcnt[b * NTB + t] = sc[t] - v;
}

// deterministic index-ordered compaction into head pairs
__global__ void hcompact_k(const uint32_t* __restrict__ keys, const uint32_t* __restrict__ Kthr,
                           const uint32_t* __restrict__ hcnt, uint2* __restrict__ headA) {
  int blk = blockIdx.x, t = threadIdx.x;
  int b = blk / NTB, c = blk % NTB;
  int v = c * 256 + t;
  size_t i = (size_t)blk * 256 + t;
  uint32_t key = keys[i];
  bool active = key <= Kthr[b];
  int w = t >> 6, lane = t & 63;
  u64 am = __ballot(active);
  uint32_t rank = (uint32_t)__popcll(am & ((1ull << lane) - 1ull));
  __shared__ uint32_t wc[4];
  if ((t & 63) == 0) wc[t >> 6] = (uint32_t)__popcll(am);
  __syncthreads();
  uint32_t off = hcnt[b * NTB + c] + rank;
  for (int w2 = 0; w2 < w; ++w2) off += wc[w2];
  if (active) headA[(size_t)b * CAP + off] = make_uint2(key, (uint32_t)v);
}

// ---------------- head radix: 4 passes x 8 bits ----------------------------
__global__ void rhist_k(const uint2* __restrict__ src, const uint32_t* __restrict__ Hlen,
                        uint32_t* __restrict__ cnt, int shift) {
  int blk = blockIdx.x, t = threadIdx.x;
  int b = blk / NBLKH, c = blk % NBLKH;
  uint32_t H = Hlen[b];
  const uint2* s = src + (size_t)b * CAP + (size_t)c * 1024;
  __shared__ uint32_t lh[256];
  lh[t] = 0;
  __syncthreads();
  #pragma unroll
  for (int e = 0; e < 4; ++e) {
    uint32_t idx = (uint32_t)(c * 1024 + 256 * e + t);
    if (idx < H) atomicAdd(&lh[(s[t + 256 * e].x >> shift) & 255u], 1u);
  }
  __syncthreads();
  cnt[((size_t)b * 256 + t) * NBLKH + c] = lh[t];
}

__launch_bounds__(1024)
__global__ void rscan_k(uint32_t* __restrict__ cnt) {
  const int NE = 256 * NBLKH;   // 24064
  const int NL = 24;
  int b = blockIdx.x, t = threadIdx.x;
  uint32_t* cc = cnt + (size_t)b * NE;
  uint32_t loc[NL];
  uint32_t s = 0;
  int base = t * NL;
  #pragma unroll
  for (int j = 0; j < NL; ++j) {
    loc[j] = (base + j < NE) ? cc[base + j] : 0u;
    s += loc[j];
  }
  __shared__ uint32_t sc[1024];
  sc[t] = s;
  __syncthreads();
  for (int off = 1; off < 1024; off <<= 1) {
    uint32_t v = (t >= off) ? sc[t - off] : 0u;
    __syncthreads();
    sc[t] += v;
    __syncthreads();
  }
  uint32_t run = sc[t] - s;
  #pragma unroll
  for (int j = 0; j < NL; ++j) {
    if (base + j < NE) { uint32_t o = loc[j]; cc[base + j] = run; run += o; }
  }
}

__launch_bounds__(256)
__global__ void rscatter_k(const uint2* __restrict__ src, uint2* __restrict__ dst,
                           const uint32_t* __restrict__ Hlen,
                           const uint32_t* __restrict__ cnt, int shift) {
  int blk = blockIdx.x, t = threadIdx.x;
  int b = blk / NBLKH, c = blk % NBLKH;
  uint32_t H = Hlen[b];
  const uint2* s = src + (size_t)b * CAP + (size_t)c * 1024;
  uint2* d = dst + (size_t)b * CAP;
  int w = t >> 6, lane = t & 63;
  __shared__ uint32_t runb[256];
  __shared__ uint32_t wvc[4][256];
  runb[t] = cnt[((size_t)b * 256 + t) * NBLKH + c];
  uint2 el[4];
  #pragma unroll
  for (int e = 0; e < 4; ++e) el[e] = s[t + 256 * e];
  u64 lowmask = (1ull << lane) - 1ull;
  #pragma unroll
  for (int e = 0; e < 4; ++e) {
    uint32_t* wf = &wvc[0][0];
    wf[t] = 0; wf[t + 256] = 0; wf[t + 512] = 0; wf[t + 768] = 0;
    __syncthreads();
    bool active = (uint32_t)(c * 1024 + 256 * e + t) < H;
    uint32_t dig = active ? ((el[e].x >> shift) & 255u) : 0u;
    u64 act = __ballot(active);
    u64 m = ~0ull;
    #pragma unroll
    for (int bit = 0; bit < 8; ++bit) {
      u64 bb = __ballot((dig >> bit) & 1u);
      m &= ((dig >> bit) & 1u) ? bb : ~bb;
    }
    m &= act;
    uint32_t rank = (uint32_t)__popcll(m & lowmask);
    if (active && rank == 0) wvc[w][dig] = (uint32_t)__popcll(m);
    __syncthreads();
    if (active) {
      uint32_t off = runb[dig] + rank;
      for (int w2 = 0; w2 < w; ++w2) off += wvc[w2][dig];
      d[off] = el[e];
    }
    __syncthreads();
    runb[t] += wvc[0][t] + wvc[1][t] + wvc[2][t] + wvc[3][t];
    __syncthreads();
  }
}

// ---------------------------------------------------------------------------
__global__ void chunks_k(const uint2* __restrict__ sp, const uint32_t* __restrict__ Hlen,
                         double* __restrict__ cs) {
  int blk = blockIdx.x, t = threadIdx.x;
  int b = blk / NBLKH, c = blk % NBLKH;
  uint32_t H = Hlen[b];
  const uint2* p = sp + (size_t)b * CAP + (size_t)c * 1024;
  double s = 0.0;
  for (int k = t; k < 1024; k += 256) {
    uint32_t idx = (uint32_t)(c * 1024 + k);
    if (idx < H) s += (double)__uint_as_float(~p[k].x);
  }
  __shared__ double red[256];
  red[t] = s; __syncthreads();
  for (int st = 128; st > 0; st >>= 1) {
    if (t < st) red[t] += red[t + st];
    __syncthreads();
  }
  if (t == 0) cs[b * NBLKH + c] = red[0];
}

// parallel cutoff: f64 chunk-scan + in-chunk f64 scan
__launch_bounds__(1024)
__global__ void cutoff_k(const uint2* __restrict__ sp, const double* __restrict__ cs,
                         const uint32_t* __restrict__ Hlen, uint32_t* __restrict__ cut) {
  int b = blockIdx.x, t = threadIdx.x;
  const double TOPP = (double)0.9f;
  uint32_t H = Hlen[b];
  __shared__ double scd[1024];
  __shared__ int chSel;
  __shared__ double baseSel;
  if (t == 0) { chSel = -1; baseSel = 0.0; }
  double v = (t < NBLKH) ? cs[b * NBLKH + t] : 0.0;
  scd[t] = v;
  __syncthreads();
  for (int off = 1; off < 1024; off <<= 1) {
    double a = (t >= off) ? scd[t - off] : 0.0;
    __syncthreads();
    scd[t] += a;
    __syncthreads();
  }
  if (t < NBLKH && scd[t] >= TOPP && (t == 0 || scd[t - 1] < TOPP)) {
    chSel = t;
    baseSel = (t == 0) ? 0.0 : scd[t - 1];
  }
  __syncthreads();
  int CH = chSel;
  if (CH < 0) { if (t == 0) cut[b] = H - 1; return; }
  double base = baseSel;
  uint32_t idx = (uint32_t)(CH * 1024 + t);
  double pv = (idx < H) ? (double)__uint_as_float(~sp[(size_t)b * CAP + idx].x) : 0.0;
  __syncthreads();
  scd[t] = pv;
  __syncthreads();
  for (int off = 1; off < 1024; off <<= 1) {
    double a = (t >= off) ? scd[t - off] : 0.0;
    __syncthreads();
    scd[t] += a;
    __syncthreads();
  }
  __shared__ int kSel;
  if (t == 0) kSel = 1023;
  __syncthreads();
  if (base + scd[t] >= TOPP && (t == 0 || base + scd[t - 1] < TOPP)) kSel = t;
  __syncthreads();
  if (t == 0) cut[b] = (uint32_t)(CH * 1024 + kSel);
}

__global__ void argmax_k(const uint2* __restrict__ sp, const uint32_t* __restrict__ cut,
                         const uint32_t* __restrict__ sk, u64* __restrict__ best) {
  const int SUB = 16;
  int b = blockIdx.x / SUB;
  int s = blockIdx.x % SUB;
  uint32_t c = cut[b];
  uint32_t k0 = sk[2 * b], k1 = sk[2 * b + 1];
  u64 loc = 0ull;
  for (uint32_t j = (uint32_t)(s * 256 + threadIdx.x); j <= c; j += SUB * 256) {
    uint32_t bits = random_bits32(k0, k1, j);
    uint32_t m = bits >> 9;
    float u = (m == 0u) ? 1.17549435e-38f : (float)m * 1.1920928955078125e-7f;
    float gum = -logf(-logf(u));
    float scv = logf(__uint_as_float(~sp[(size_t)b * CAP + j].x)) + gum;
    uint32_t su = __float_as_uint(scv);
    uint32_t ord = (su & 0x80000000u) ? ~su : (su | 0x80000000u);
    u64 pk = ((u64)ord << 32) | (u64)(0xFFFFFFFFu - j);
    loc = (pk > loc) ? pk : loc;
  }
  __shared__ u64 red[256];
  red[threadIdx.x] = loc;
  __syncthreads();
  for (int st = 128; st > 0; st >>= 1) {
    if (threadIdx.x < st) {
      u64 o = red[threadIdx.x + st];
      if (o > red[threadIdx.x]) red[threadIdx.x] = o;
    }
    __syncthreads();
  }
  if (threadIdx.x == 0) atomicMax(best + b, red[0]);
}

__global__ void fill_k(float* __restrict__ out) {
  size_t i = (size_t)blockIdx.x * 256 + threadIdx.x;
  out[i] = 1e-5f;
}

__global__ void win_k(const u64* __restrict__ best, const uint2* __restrict__ sp,
                      float* __restrict__ out) {
  int b = threadIdx.x;
  if (b >= NB) return;
  u64 pk = best[b];
  uint32_t j = 0xFFFFFFFFu - (uint32_t)(pk & 0xFFFFFFFFull);
  uint32_t tok = sp[(size_t)b * CAP + j].y;
  out[(size_t)b * NV + tok] = 100000.0f;
}

// ---------------------------------------------------------------------------
extern "C" void kernel_launch(void* const* d_in, const int* in_sizes, int n_in,
                              void* d_out, int out_size, void* d_ws, size_t ws_size,
                              hipStream_t stream) {
  const int* ids = (const int*)d_in[0];
  const float* logits = (const float*)d_in[1];
  float* out = (float*)d_out;
  int T = in_sizes[0] / NB;

  char* w = (char*)d_ws;
  uint2*    headA = (uint2*)(w + 0);                  // 24,641,536
  uint2*    headB = (uint2*)(w + 24641536);           // 24,641,536
  uint16_t* mask  = (uint16_t*)(w + 49283072);        //  8,192,000
  // aliases:
  uint32_t* keys  = (uint32_t*)(w + 24641536);        // 16,384,000 in headB (dead before radix pass1)
  uint32_t* cnt   = (uint32_t*)(w + 49283072);        // 3,080,192 in mask region (mask dead after final+hcompact reads? no: cnt written in radix, after hcompact — mask last read in final_k ✓)
  double*   csum  = (double*)(w + 52400000);          // 24,064 in mask region
  uint32_t* cut   = (uint32_t*)(w + 52430080);        // 128 in mask region
  // non-aliased smalls:
  char* S = w + 57475072;
  float*    pmax    = (float*)(S + 0);                // 64,000
  uint32_t* hcnt    = (uint32_t*)(S + 64000);         // 64,000
  float*    mx      = (float*)(S + 128000);           // 128
  float*    zf      = (float*)(S + 128128);           // 128
  float*    gm      = (float*)(S + 128256);           // 2,048
  uint32_t* kd      = (uint32_t*)(S + 130304);        // 4,096
  uint32_t* sk      = (uint32_t*)(S + 134400);        // 256
  u64*      best    = (u64*)(S + 134656);             // 256
  uint32_t* Kthr    = (uint32_t*)(S + 134912);        // 128
  uint32_t* Hlen    = (uint32_t*)(S + 135040);        // 128
  u64*      Zint    = (u64*)(S + 135168);             // 256
  float*    wloTab  = (float*)(S + 135424);           // 32,768
  // zero region (one memset), 8B-aligned: S+168192
  char* ZR = S + 168192;
  u64*      Hlo     = (u64*)(ZR + 0);                 // 65,536
  u64*      Thist   = (u64*)(ZR + 65536);             // 65,536
  u64*      binmass = (u64*)(ZR + 131072);            // 131,072
  uint32_t* bincnt  = (uint32_t*)(ZR + 262144);       // 65,536
  // total: 57,475,072 + 168,192 + 327,680 = 57,970,944 bytes

  const int BVBLK = NB * NTB;   // 16,000

  hipMemsetAsync(ZR, 0, 327680, stream);
  keys_k<<<1, 64, 0, stream>>>(ids, T, kd, sk, best);
  gmaskmax_k<<<BVBLK, 256, 0, stream>>>(kd, logits, mask, pmax);
  maxr2_k<<<1, 1024, 0, stream>>>(pmax, mx);
  lohist_k<<<BVBLK, 256, 0, stream>>>(logits, mask, mx, Hlo);
  faclo_k<<<NB, 256, 0, stream>>>(Hlo, Zint, zf, gm, wloTab);
  hihist_k<<<BVBLK, 256, 0, stream>>>(logits, mask, mx, wloTab, Thist);
  fachi_k<<<NB, 256, 0, stream>>>(Thist, Zint, gm);
  final_k<<<BVBLK, 256, 0, stream>>>(logits, mask, mx, zf, gm, keys, binmass, bincnt);
  binsel_k<<<NB, NBINS, 0, stream>>>(binmass, bincnt, Kthr, Hlen);
  hcount_k<<<BVBLK, 256, 0, stream>>>(keys, Kthr, hcnt);
  hscan_k<<<NB, 1024, 0, stream>>>(hcnt);
  hcompact_k<<<BVBLK, 256, 0, stream>>>(keys, Kthr, hcnt, headA);

  const uint2* srcs[4] = { headA, headB, headA, headB };
  uint2*       dsts[4] = { headB, headA, headB, headA };
  for (int pass = 0; pass < 4; ++pass) {
    int shift = pass * 8;
    rhist_k<<<NB * NBLKH, 256, 0, stream>>>(srcs[pass], Hlen, cnt, shift);
    rscan_k<<<NB, 1024, 0, stream>>>(cnt);
    rscatter_k<<<NB * NBLKH, 256, 0, stream>>>(srcs[pass], dsts[pass], Hlen, cnt, shift);
  }

  chunks_k<<<NB * NBLKH, 256, 0, stream>>>(headA, Hlen, csum);
  cutoff_k<<<NB, 1024, 0, stream>>>(headA, csum, Hlen, cut);
  argmax_k<<<NB * 16, 256, 0, stream>>>(headA, cut, sk, best);
  fill_k<<<BVBLK, 256, 0, stream>>>(out);
  win_k<<<1, 32, 0, stream>>>(best, headA, out);
}

// Round 5
// 545.275 us; speedup vs baseline: 6.9102x; 1.0126x over previous
//
#include <hip/hip_runtime.h>
#include <stdint.h>

// ============================================================================
// SynthID watermark processor — round 5: SGPR-key unrolled threefry, early-exit
// head radix, 1-bin binsel margin, exp cache, fused cutoff+argmax.
// RNG: jax_threefry_partitionable=True (validated r1-r4).
// ============================================================================

#define NB 32
#define NV 128000
#define NDEPTH 16
#define NTB 500        // 256-token blocks per batch
#define NBINS 512      // exponent bins = key >> 23
#define CAP 96256      // head capacity per batch (94*1024)
#define NBLKH 94       // head radix blocks (1024 elems each) per batch
#define FPSCALE 17592186044416.0          // 2^44 (p0 fixed point)
#define TSCALE  68719476736.0             // 2^36 (weighted mass fixed point)
#define MSCALE 1.152921504606846976e18    // 2^60 (bin mass)

typedef unsigned long long u64;

__device__ __forceinline__ uint32_t rotl32(uint32_t v, int r) {
  return (v << r) | (v >> (32 - r));
}

__device__ __forceinline__ void tf2x32(uint32_t k0, uint32_t k1,
                                       uint32_t x0, uint32_t x1,
                                       uint32_t &o0, uint32_t &o1) {
  uint32_t ks2 = k0 ^ k1 ^ 0x1BD11BDAu;
  x0 += k0; x1 += k1;
  x0 += x1; x1 = rotl32(x1, 13); x1 ^= x0;
  x0 += x1; x1 = rotl32(x1, 15); x1 ^= x0;
  x0 += x1; x1 = rotl32(x1, 26); x1 ^= x0;
  x0 += x1; x1 = rotl32(x1,  6); x1 ^= x0;
  x0 += k1; x1 += ks2 + 1u;
  x0 += x1; x1 = rotl32(x1, 17); x1 ^= x0;
  x0 += x1; x1 = rotl32(x1, 29); x1 ^= x0;
  x0 += x1; x1 = rotl32(x1, 16); x1 ^= x0;
  x0 += x1; x1 = rotl32(x1, 24); x1 ^= x0;
  x0 += ks2; x1 += k0 + 2u;
  x0 += x1; x1 = rotl32(x1, 13); x1 ^= x0;
  x0 += x1; x1 = rotl32(x1, 15); x1 ^= x0;
  x0 += x1; x1 = rotl32(x1, 26); x1 ^= x0;
  x0 += x1; x1 = rotl32(x1,  6); x1 ^= x0;
  x0 += k0; x1 += k1 + 3u;
  x0 += x1; x1 = rotl32(x1, 17); x1 ^= x0;
  x0 += x1; x1 = rotl32(x1, 29); x1 ^= x0;
  x0 += x1; x1 = rotl32(x1, 16); x1 ^= x0;
  x0 += x1; x1 = rotl32(x1, 24); x1 ^= x0;
  x0 += k1; x1 += ks2 + 4u;
  x0 += x1; x1 = rotl32(x1, 13); x1 ^= x0;
  x0 += x1; x1 = rotl32(x1, 15); x1 ^= x0;
  x0 += x1; x1 = rotl32(x1, 26); x1 ^= x0;
  x0 += x1; x1 = rotl32(x1,  6); x1 ^= x0;
  x0 += ks2; x1 += k0 + 5u;
  o0 = x0; o1 = x1;
}

__device__ __forceinline__ uint32_t random_bits32(uint32_t k0, uint32_t k1, uint32_t i) {
  uint32_t y0, y1;
  tf2x32(k0, k1, 0u, i, y0, y1);
  return y0 ^ y1;
}

// ---------------------------------------------------------------------------
__global__ void keys_k(const int* __restrict__ ids, int T,
                       uint32_t* __restrict__ kd, uint32_t* __restrict__ sk) {
  int t = threadIdx.x;
  if (t >= NB) return;
  uint32_t prior = 0;
  for (int q = 0; q < 4; ++q) prior += (uint32_t)ids[(size_t)t * T + (T - 4) + q];
  uint32_t b0, b1;
  tf2x32(0u, 0u, 0u, prior, b0, b1);
  for (int d = 0; d < NDEPTH; ++d) {
    uint32_t y0, y1;
    tf2x32(b0, b1, 0u, (uint32_t)d, y0, y1);
    kd[(t * NDEPTH + d) * 2 + 0] = y0;
    kd[(t * NDEPTH + d) * 2 + 1] = y1;
  }
  uint32_t s0, s1;
  tf2x32(0u, 1u, 0u, (uint32_t)t, s0, s1);
  sk[2 * t + 0] = s0;
  sk[2 * t + 1] = s1;
}

// gmask (SGPR keys, fully unrolled) + per-256-token block max of logits
__global__ void gmaskmax_k(const uint32_t* __restrict__ kd, const float* __restrict__ logits,
                           uint16_t* __restrict__ mask, float* __restrict__ pmax) {
  int blk = blockIdx.x, t = threadIdx.x;
  int b = blk / NTB, c = blk % NTB;
  uint32_t v = (uint32_t)(c * 256 + t);
  size_t i = (size_t)b * NV + v;
  const uint32_t* kp = kd + b * NDEPTH * 2;
  uint32_t m = 0;
  #pragma unroll
  for (int d = 0; d < NDEPTH; ++d) {
    uint32_t k0 = __builtin_amdgcn_readfirstlane(kp[2 * d]);
    uint32_t k1 = __builtin_amdgcn_readfirstlane(kp[2 * d + 1]);
    uint32_t bits = random_bits32(k0, k1, v);
    m |= ((bits >> 31) ^ 1u) << d;   // bernoulli(0.5) true <=> top bit 0
  }
  mask[i] = (uint16_t)m;
  // block max via wave shfl + 4-entry LDS
  float x = logits[i];
  for (int o = 32; o > 0; o >>= 1) x = fmaxf(x, __shfl_xor(x, o));
  __shared__ float wmax[4];
  if ((t & 63) == 0) wmax[t >> 6] = x;
  __syncthreads();
  if (t == 0) pmax[b * NTB + c] = fmaxf(fmaxf(wmax[0], wmax[1]), fmaxf(wmax[2], wmax[3]));
}

__global__ void maxr2_k(const float* __restrict__ pmax, float* __restrict__ mx) {
  int t = threadIdx.x;
  int b = t >> 5, k = t & 31;
  float m = -3.4e38f;
  for (int i = k; i < NTB; i += 32) m = fmaxf(m, pmax[b * NTB + i]);
  for (int o = 16; o > 0; o >>= 1) m = fmaxf(m, __shfl_xor(m, o, 32));
  if (k == 0) mx[b] = m;
}

// 256-bin low-byte histogram of fixed-point p0; also caches ef = expf(x-mx)
__global__ void lohist_k(const float* __restrict__ logits, const uint16_t* __restrict__ mask,
                         const float* __restrict__ mx, float* __restrict__ ef,
                         u64* __restrict__ Hlo) {
  int blk = blockIdx.x, t = threadIdx.x;
  int b = blk / NTB;
  __shared__ u64 h[256];
  h[t] = 0ull;
  __syncthreads();
  size_t i = (size_t)blk * 256 + t;
  float e = expf(logits[i] - mx[b]);
  ef[i] = e;
  u64 q = (u64)((double)e * FPSCALE);
  atomicAdd(&h[mask[i] & 255u], q);
  __syncthreads();
  if (h[t]) atomicAdd(&Hlo[b * 256 + t], h[t]);
}

// depths 0..7 on the 256-entry low histogram; exact integer Z; emits W_lo table
__global__ void faclo_k(const u64* __restrict__ Hlo, u64* __restrict__ Zint,
                        float* __restrict__ zf, float* __restrict__ gm,
                        float* __restrict__ wloTab) {
  int b = blockIdx.x, t = threadIdx.x;
  u64 v = Hlo[b * 256 + t];
  __shared__ u64 zr[256];
  zr[t] = v; __syncthreads();
  for (int s = 128; s > 0; s >>= 1) { if (t < s) zr[t] += zr[t + s]; __syncthreads(); }
  __shared__ double Zsh;
  if (t == 0) {
    Zint[b] = zr[0];
    Zsh = (double)zr[0] * (1.0 / FPSCALE);
    zf[b] = (float)Zsh;
  }
  __syncthreads();
  double Zd = Zsh;
  float base = (float)((double)v * (1.0 / FPSCALE) / Zd);
  float w = 1.0f;
  __shared__ double dr[256];
  for (int d = 0; d < 8; ++d) {
    int bit = (t >> d) & 1;
    dr[t] = bit ? (double)(base * w) : 0.0;
    __syncthreads();
    for (int s = 128; s > 0; s >>= 1) { if (t < s) dr[t] += dr[t + s]; __syncthreads(); }
    float g = (float)dr[0];
    if (t == 0) gm[b * NDEPTH + d] = g;
    w *= (1.0f + (float)bit) - g;
    __syncthreads();
  }
  wloTab[b * 256 + t] = w;
}

// 256-bin high-byte histogram of p0 * W_lo(lo)  (fixed-point 2^36)
__global__ void hihist_k(const float* __restrict__ ef, const uint16_t* __restrict__ mask,
                         const float* __restrict__ wloTab, u64* __restrict__ Thist) {
  int blk = blockIdx.x, t = threadIdx.x;
  int b = blk / NTB;
  __shared__ u64 h[256];
  __shared__ float wl[256];
  h[t] = 0ull;
  wl[t] = wloTab[b * 256 + t];
  __syncthreads();
  size_t i = (size_t)blk * 256 + t;
  float e = ef[i];
  uint32_t mk = mask[i];
  double prod = (double)e * (double)wl[mk & 255u];
  atomicAdd(&h[mk >> 8], (u64)(prod * TSCALE));
  __syncthreads();
  if (h[t]) atomicAdd(&Thist[b * 256 + t], h[t]);
}

// depths 8..15 on the 256-entry weighted high histogram
__global__ void fachi_k(const u64* __restrict__ Thist, const u64* __restrict__ Zint,
                        float* __restrict__ gm) {
  int b = blockIdx.x, t = threadIdx.x;
  double Zd = (double)Zint[b] * (1.0 / FPSCALE);
  u64 v = Thist[b * 256 + t];
  float base = (float)((double)v * (1.0 / TSCALE) / Zd);
  float w = 1.0f;
  __shared__ double dr[256];
  for (int d = 8; d < NDEPTH; ++d) {
    int bit = (t >> (d - 8)) & 1;
    dr[t] = bit ? (double)(base * w) : 0.0;
    __syncthreads();
    for (int s = 128; s > 0; s >>= 1) { if (t < s) dr[t] += dr[t + s]; __syncthreads(); }
    float g = (float)dr[0];
    if (t == 0) gm[b * NDEPTH + d] = g;
    w *= (1.0f + (float)bit) - g;
    __syncthreads();
  }
}

// final p (exact per-token chain) -> keys (overwrites ef in place) + 512-bin histos
__global__ void final_k(float* __restrict__ efkeys, const uint16_t* __restrict__ mask,
                        const float* __restrict__ zf, const float* __restrict__ gm,
                        u64* __restrict__ binmass, uint32_t* __restrict__ bincnt) {
  int b = blockIdx.x / NTB;
  int t = threadIdx.x;
  __shared__ float gsh[NDEPTH];
  __shared__ float zsh;
  __shared__ u64 bm[NBINS];
  __shared__ uint32_t bc[NBINS];
  if (t < NDEPTH) gsh[t] = gm[b * NDEPTH + t];
  if (t == 16) zsh = zf[b];
  for (int i = t; i < NBINS; i += 256) { bm[i] = 0ull; bc[i] = 0u; }
  __syncthreads();
  size_t i = (size_t)blockIdx.x * 256 + t;
  float p = efkeys[i] / zsh;
  uint16_t mk = mask[i];
  #pragma unroll
  for (int d = 0; d < NDEPTH; ++d) {
    float g = (float)((mk >> d) & 1);
    p = p * ((1.0f + g) - gsh[d]);
  }
  uint32_t key = ~__float_as_uint(p);
  ((uint32_t*)efkeys)[i] = key;   // same address read above -> safe overlay
  uint32_t bin = key >> 23;
  atomicAdd(&bm[bin], (u64)((double)p * MSCALE));
  atomicAdd(&bc[bin], 1u);
  __syncthreads();
  for (int k = t; k < NBINS; k += 256) {
    if (bc[k]) atomicAdd(&bincnt[b * NBINS + k], bc[k]);
    if (bm[k]) atomicAdd(&binmass[b * NBINS + k], bm[k]);
  }
}

// pick head threshold: first bin crossing absolute 0.9f mass, +1 bin margin
__launch_bounds__(512)
__global__ void binsel_k(const u64* __restrict__ binmass, const uint32_t* __restrict__ bincnt,
                         uint32_t* __restrict__ Kthr, uint32_t* __restrict__ Hlen) {
  int b = blockIdx.x, t = threadIdx.x;
  __shared__ u64 cm[NBINS];
  __shared__ uint32_t cc[NBINS];
  __shared__ int selB;
  cm[t] = binmass[b * NBINS + t];
  cc[t] = bincnt[b * NBINS + t];
  if (t == 0) selB = NBINS - 2;
  __syncthreads();
  for (int off = 1; off < NBINS; off <<= 1) {
    u64 a = (t >= off) ? cm[t - off] : 0ull;
    uint32_t d = (t >= off) ? cc[t - off] : 0u;
    __syncthreads();
    cm[t] += a; cc[t] += d;
    __syncthreads();
  }
  const u64 thr = (u64)((double)0.9f * MSCALE);
  if (cm[t] >= thr && (t == 0 || cm[t - 1] < thr)) atomicMin(&selB, t);
  __syncthreads();
  if (t == 0) {
    int Bs = selB + 1;
    if (Bs > NBINS - 1) Bs = NBINS - 1;
    while (Bs > 0 && cc[Bs] > CAP) --Bs;
    u64 kt = (((u64)(Bs + 1)) << 23) - 1ull;
    Kthr[b] = (uint32_t)kt;
    Hlen[b] = cc[Bs];
  }
}

// per-256-chunk head-element counts
__global__ void hcount_k(const uint32_t* __restrict__ keys, const uint32_t* __restrict__ Kthr,
                         uint32_t* __restrict__ hcnt) {
  int blk = blockIdx.x, t = threadIdx.x;
  int b = blk / NTB, c = blk % NTB;
  size_t i = (size_t)blk * 256 + t;
  bool active = keys[i] <= Kthr[b];
  u64 am = __ballot(active);
  __shared__ uint32_t wc[4];
  if ((t & 63) == 0) wc[t >> 6] = (uint32_t)__popcll(am);
  __syncthreads();
  if (t == 0) hcnt[b * NTB + c] = wc[0] + wc[1] + wc[2] + wc[3];
}

// exclusive scan of the 500 per-chunk counts (in place)
__launch_bounds__(1024)
__global__ void hscan_k(uint32_t* __restrict__ hcnt) {
  int b = blockIdx.x, t = threadIdx.x;
  uint32_t v = (t < NTB) ? hcnt[b * NTB + t] : 0u;
  __shared__ uint32_t sc[1024];
  sc[t] = v;
  __syncthreads();
  for (int off = 1; off < 1024; off <<= 1) {
    uint32_t a = (t >= off) ? sc[t - off] : 0u;
    __syncthreads();
    sc[t] += a;
    __syncthreads();
  }
  if (t < NTB) hcnt[b * NTB + t] = sc[t] - v;
}

// deterministic index-ordered compaction into head pairs
__global__ void hcompact_k(const uint32_t* __restrict__ keys, const uint32_t* __restrict__ Kthr,
                           const uint32_t* __restrict__ hcnt, uint2* __restrict__ headA) {
  int blk = blockIdx.x, t = threadIdx.x;
  int b = blk / NTB, c = blk % NTB;
  int v = c * 256 + t;
  size_t i = (size_t)blk * 256 + t;
  uint32_t key = keys[i];
  bool active = key <= Kthr[b];
  int w = t >> 6, lane = t & 63;
  u64 am = __ballot(active);
  uint32_t rank = (uint32_t)__popcll(am & ((1ull << lane) - 1ull));
  __shared__ uint32_t wc[4];
  if ((t & 63) == 0) wc[t >> 6] = (uint32_t)__popcll(am);
  __syncthreads();
  uint32_t off = hcnt[b * NTB + c] + rank;
  for (int w2 = 0; w2 < w; ++w2) off += wc[w2];
  if (active) headA[(size_t)b * CAP + off] = make_uint2(key, (uint32_t)v);
}

// ---------------- head radix: 4 passes x 8 bits (early-exit) ---------------
__global__ void rhist_k(const uint2* __restrict__ src, const uint32_t* __restrict__ Hlen,
                        uint32_t* __restrict__ cnt, int shift) {
  int blk = blockIdx.x, t = threadIdx.x;
  int b = blk / NBLKH, c = blk % NBLKH;
  uint32_t H = Hlen[b];
  if ((uint32_t)(c * 1024) >= H) { cnt[((size_t)b * 256 + t) * NBLKH + c] = 0u; return; }
  const uint2* s = src + (size_t)b * CAP + (size_t)c * 1024;
  __shared__ uint32_t lh[256];
  lh[t] = 0;
  __syncthreads();
  #pragma unroll
  for (int e = 0; e < 4; ++e) {
    uint32_t idx = (uint32_t)(c * 1024 + 256 * e + t);
    if (idx < H) atomicAdd(&lh[(s[t + 256 * e].x >> shift) & 255u], 1u);
  }
  __syncthreads();
  cnt[((size_t)b * 256 + t) * NBLKH + c] = lh[t];
}

__launch_bounds__(1024)
__global__ void rscan_k(uint32_t* __restrict__ cnt) {
  const int NE = 256 * NBLKH;   // 24064
  const int NL = 24;
  int b = blockIdx.x, t = threadIdx.x;
  uint32_t* cc = cnt + (size_t)b * NE;
  uint32_t loc[NL];
  uint32_t s = 0;
  int base = t * NL;
  #pragma unroll
  for (int j = 0; j < NL; ++j) {
    loc[j] = (base + j < NE) ? cc[base + j] : 0u;
    s += loc[j];
  }
  __shared__ uint32_t sc[1024];
  sc[t] = s;
  __syncthreads();
  for (int off = 1; off < 1024; off <<= 1) {
    uint32_t v = (t >= off) ? sc[t - off] : 0u;
    __syncthreads();
    sc[t] += v;
    __syncthreads();
  }
  uint32_t run = sc[t] - s;
  #pragma unroll
  for (int j = 0; j < NL; ++j) {
    if (base + j < NE) { uint32_t o = loc[j]; cc[base + j] = run; run += o; }
  }
}

__launch_bounds__(256)
__global__ void rscatter_k(const uint2* __restrict__ src, uint2* __restrict__ dst,
                           const uint32_t* __restrict__ Hlen,
                           const uint32_t* __restrict__ cnt, int shift) {
  int blk = blockIdx.x, t = threadIdx.x;
  int b = blk / NBLKH, c = blk % NBLKH;
  uint32_t H = Hlen[b];
  if ((uint32_t)(c * 1024) >= H) return;
  const uint2* s = src + (size_t)b * CAP + (size_t)c * 1024;
  uint2* d = dst + (size_t)b * CAP;
  int w = t >> 6, lane = t & 63;
  __shared__ uint32_t runb[256];
  __shared__ uint32_t wvc[4][256];
  runb[t] = cnt[((size_t)b * 256 + t) * NBLKH + c];
  uint2 el[4];
  #pragma unroll
  for (int e = 0; e < 4; ++e) el[e] = s[t + 256 * e];
  u64 lowmask = (1ull << lane) - 1ull;
  #pragma unroll
  for (int e = 0; e < 4; ++e) {
    uint32_t* wf = &wvc[0][0];
    wf[t] = 0; wf[t + 256] = 0; wf[t + 512] = 0; wf[t + 768] = 0;
    __syncthreads();
    bool active = (uint32_t)(c * 1024 + 256 * e + t) < H;
    uint32_t dig = active ? ((el[e].x >> shift) & 255u) : 0u;
    u64 act = __ballot(active);
    u64 m = ~0ull;
    #pragma unroll
    for (int bit = 0; bit < 8; ++bit) {
      u64 bb = __ballot((dig >> bit) & 1u);
      m &= ((dig >> bit) & 1u) ? bb : ~bb;
    }
    m &= act;
    uint32_t rank = (uint32_t)__popcll(m & lowmask);
    if (active && rank == 0) wvc[w][dig] = (uint32_t)__popcll(m);
    __syncthreads();
    if (active) {
      uint32_t off = runb[dig] + rank;
      for (int w2 = 0; w2 < w; ++w2) off += wvc[w2][dig];
      d[off] = el[e];
    }
    __syncthreads();
    runb[t] += wvc[0][t] + wvc[1][t] + wvc[2][t] + wvc[3][t];
    __syncthreads();
  }
}

// ---------------------------------------------------------------------------
__global__ void chunks_k(const uint2* __restrict__ sp, const uint32_t* __restrict__ Hlen,
                         double* __restrict__ cs) {
  int blk = blockIdx.x, t = threadIdx.x;
  int b = blk / NBLKH, c = blk % NBLKH;
  uint32_t H = Hlen[b];
  if ((uint32_t)(c * 1024) >= H) { if (t == 0) cs[b * NBLKH + c] = 0.0; return; }
  const uint2* p = sp + (size_t)b * CAP + (size_t)c * 1024;
  double s = 0.0;
  for (int k = t; k < 1024; k += 256) {
    uint32_t idx = (uint32_t)(c * 1024 + k);
    if (idx < H) s += (double)__uint_as_float(~p[k].x);
  }
  __shared__ double red[256];
  red[t] = s; __syncthreads();
  for (int st = 128; st > 0; st >>= 1) {
    if (t < st) red[t] += red[t + st];
    __syncthreads();
  }
  if (t == 0) cs[b * NBLKH + c] = red[0];
}

// fused: parallel cutoff (f64 chunk scan + in-chunk scan) then gumbel argmax
__launch_bounds__(1024)
__global__ void cutargmax_k(const uint2* __restrict__ sp, const double* __restrict__ cs,
                            const uint32_t* __restrict__ Hlen,
                            const uint32_t* __restrict__ sk, u64* __restrict__ best) {
  int b = blockIdx.x, t = threadIdx.x;
  const double TOPP = (double)0.9f;
  uint32_t H = Hlen[b];
  __shared__ double scd[1024];
  __shared__ int chSel;
  __shared__ double baseSel;
  __shared__ uint32_t cutSh;
  if (t == 0) { chSel = -1; baseSel = 0.0; cutSh = H - 1; }
  double v = (t < NBLKH) ? cs[b * NBLKH + t] : 0.0;
  scd[t] = v;
  __syncthreads();
  for (int off = 1; off < 1024; off <<= 1) {
    double a = (t >= off) ? scd[t - off] : 0.0;
    __syncthreads();
    scd[t] += a;
    __syncthreads();
  }
  if (t < NBLKH && scd[t] >= TOPP && (t == 0 || scd[t - 1] < TOPP)) {
    chSel = t;
    baseSel = (t == 0) ? 0.0 : scd[t - 1];
  }
  __syncthreads();
  int CH = chSel;
  if (CH >= 0) {
    double base = baseSel;
    uint32_t idx = (uint32_t)(CH * 1024 + t);
    double pv = (idx < H) ? (double)__uint_as_float(~sp[(size_t)b * CAP + idx].x) : 0.0;
    __syncthreads();
    scd[t] = pv;
    __syncthreads();
    for (int off = 1; off < 1024; off <<= 1) {
      double a = (t >= off) ? scd[t - off] : 0.0;
      __syncthreads();
      scd[t] += a;
      __syncthreads();
    }
    __shared__ int kSel;
    if (t == 0) kSel = 1023;
    __syncthreads();
    if (base + scd[t] >= TOPP && (t == 0 || base + scd[t - 1] < TOPP)) kSel = t;
    __syncthreads();
    if (t == 0) cutSh = (uint32_t)(CH * 1024 + kSel);
  }
  __syncthreads();
  // ---- argmax phase ----
  uint32_t c = cutSh;
  uint32_t k0 = sk[2 * b], k1 = sk[2 * b + 1];
  u64 loc = 0ull;
  for (uint32_t j = (uint32_t)t; j <= c; j += 1024) {
    uint32_t bits = random_bits32(k0, k1, j);
    uint32_t m = bits >> 9;
    float u = (m == 0u) ? 1.17549435e-38f : (float)m * 1.1920928955078125e-7f;
    float gum = -logf(-logf(u));
    float scv = logf(__uint_as_float(~sp[(size_t)b * CAP + j].x)) + gum;
    uint32_t su = __float_as_uint(scv);
    uint32_t ord = (su & 0x80000000u) ? ~su : (su | 0x80000000u);
    u64 pk = ((u64)ord << 32) | (u64)(0xFFFFFFFFu - j);
    loc = (pk > loc) ? pk : loc;
  }
  __shared__ u64 redm[1024];
  redm[t] = loc;
  __syncthreads();
  for (int st = 512; st > 0; st >>= 1) {
    if (t < st) {
      u64 o = redm[t + st];
      if (o > redm[t]) redm[t] = o;
    }
    __syncthreads();
  }
  if (t == 0) best[b] = redm[0];
}

__global__ void fill_k(float* __restrict__ out) {
  size_t i = (size_t)blockIdx.x * 256 + threadIdx.x;
  out[i] = 1e-5f;
}

__global__ void win_k(const u64* __restrict__ best, const uint2* __restrict__ sp,
                      float* __restrict__ out) {
  int b = threadIdx.x;
  if (b >= NB) return;
  u64 pk = best[b];
  uint32_t j = 0xFFFFFFFFu - (uint32_t)(pk & 0xFFFFFFFFull);
  uint32_t tok = sp[(size_t)b * CAP + j].y;
  out[(size_t)b * NV + tok] = 100000.0f;
}

// ---------------------------------------------------------------------------
extern "C" void kernel_launch(void* const* d_in, const int* in_sizes, int n_in,
                              void* d_out, int out_size, void* d_ws, size_t ws_size,
                              hipStream_t stream) {
  const int* ids = (const int*)d_in[0];
  const float* logits = (const float*)d_in[1];
  float* out = (float*)d_out;
  int T = in_sizes[0] / NB;

  char* w = (char*)d_ws;
  uint2*    headA = (uint2*)(w + 0);                  // 24,641,536
  uint2*    headB = (uint2*)(w + 24641536);           // 24,641,536
  uint16_t* mask  = (uint16_t*)(w + 49283072);        //  8,192,000
  // aliases:
  float*    efkeys = (float*)(w + 24641536);          // 16,384,000 in headB: ef then keys (in-place), dead before radix pass1 scatter
  uint32_t* keys   = (uint32_t*)(w + 24641536);
  uint32_t* cnt    = (uint32_t*)(w + 49283072);       // 3,080,192 in mask region (mask dead after final_k)
  double*   csum   = (double*)(w + 52400000);         // 24,064 in mask region
  // non-aliased smalls:
  char* S = w + 57475072;
  float*    pmax    = (float*)(S + 0);                // 64,000
  uint32_t* hcnt    = (uint32_t*)(S + 64000);         // 64,000
  float*    mx      = (float*)(S + 128000);           // 128
  float*    zf      = (float*)(S + 128128);           // 128
  float*    gm      = (float*)(S + 128256);           // 2,048
  uint32_t* kd      = (uint32_t*)(S + 130304);        // 4,096
  uint32_t* sk      = (uint32_t*)(S + 134400);        // 256
  u64*      best    = (u64*)(S + 134656);             // 256
  uint32_t* Kthr    = (uint32_t*)(S + 134912);        // 128
  uint32_t* Hlen    = (uint32_t*)(S + 135040);        // 128
  u64*      Zint    = (u64*)(S + 135168);             // 256
  float*    wloTab  = (float*)(S + 135424);           // 32,768
  // zero region (one memset), 8B-aligned:
  char* ZR = S + 168192;
  u64*      Hlo     = (u64*)(ZR + 0);                 // 65,536
  u64*      Thist   = (u64*)(ZR + 65536);             // 65,536
  u64*      binmass = (u64*)(ZR + 131072);            // 131,072
  uint32_t* bincnt  = (uint32_t*)(ZR + 262144);       // 65,536

  const int BVBLK = NB * NTB;   // 16,000

  hipMemsetAsync(ZR, 0, 327680, stream);
  keys_k<<<1, 64, 0, stream>>>(ids, T, kd, sk);
  gmaskmax_k<<<BVBLK, 256, 0, stream>>>(kd, logits, mask, pmax);
  maxr2_k<<<1, 1024, 0, stream>>>(pmax, mx);
  lohist_k<<<BVBLK, 256, 0, stream>>>(logits, mask, mx, efkeys, Hlo);
  faclo_k<<<NB, 256, 0, stream>>>(Hlo, Zint, zf, gm, wloTab);
  hihist_k<<<BVBLK, 256, 0, stream>>>(efkeys, mask, wloTab, Thist);
  fachi_k<<<NB, 256, 0, stream>>>(Thist, Zint, gm);
  final_k<<<BVBLK, 256, 0, stream>>>(efkeys, mask, zf, gm, binmass, bincnt);
  binsel_k<<<NB, NBINS, 0, stream>>>(binmass, bincnt, Kthr, Hlen);
  hcount_k<<<BVBLK, 256, 0, stream>>>(keys, Kthr, hcnt);
  hscan_k<<<NB, 1024, 0, stream>>>(hcnt);
  hcompact_k<<<BVBLK, 256, 0, stream>>>(keys, Kthr, hcnt, headA);

  const uint2* srcs[4] = { headA, headB, headA, headB };
  uint2*       dsts[4] = { headB, headA, headB, headA };
  for (int pass = 0; pass < 4; ++pass) {
    int shift = pass * 8;
    rhist_k<<<NB * NBLKH, 256, 0, stream>>>(srcs[pass], Hlen, cnt, shift);
    rscan_k<<<NB, 1024, 0, stream>>>(cnt);
    rscatter_k<<<NB * NBLKH, 256, 0, stream>>>(srcs[pass], dsts[pass], Hlen, cnt, shift);
  }

  chunks_k<<<NB * NBLKH, 256, 0, stream>>>(headA, Hlen, csum);
  cutargmax_k<<<NB, 1024, 0, stream>>>(headA, csum, Hlen, sk, best);
  fill_k<<<BVBLK, 256, 0, stream>>>(out);
  win_k<<<1, 32, 0, stream>>>(best, headA, out);
}